// Round 1
// baseline (1545.932 us; speedup 1.0000x reference)
//
#include <hip/hip_runtime.h>
#include <math.h>

#define HID 128
#define NH 8
#define HD 16

__device__ __forceinline__ float gelu_f(float x) {
    float x3 = x*x*x;
    return 0.5f*x*(1.f + tanhf(0.7978845608028654f*(x + 0.044715f*x3)));
}

// C[N x 128] = op(A[N x K]) @ W[K x 128] + bias
// MODE 0: plain. MODE 1: gelu on A elements; epilogue out = beta*C + (1-beta)*res
template<int MODE>
__global__ __launch_bounds__(256) void gemm128(
    const float* __restrict__ A, const float* __restrict__ W,
    const float* __restrict__ bias, float* __restrict__ Cout,
    int N, int K,
    const float* __restrict__ res, const float* __restrict__ skipv)
{
    __shared__ float As[32][68];    // A tile transposed: As[k][row]
    __shared__ float Ws[32][132];   // W tile: Ws[k][col]
    int tid = threadIdx.x;
    int row0 = (tid >> 4) * 4;
    int col0 = (tid & 15) * 8;
    int block_row = blockIdx.x * 64;
    float acc[4][8];
    #pragma unroll
    for (int i=0;i<4;i++)
        #pragma unroll
        for (int j=0;j<8;j++) acc[i][j]=0.f;

    int lc4 = (tid & 7) * 4;
    int lr  = tid >> 3;
    int wc4 = (tid & 31) * 4;
    int wr  = tid >> 5;

    for (int k0 = 0; k0 < K; k0 += 32) {
        #pragma unroll
        for (int rr = 0; rr < 2; rr++) {
            int row = lr + rr*32;
            int grow = block_row + row;
            float4 v = make_float4(0.f,0.f,0.f,0.f);
            if (grow < N) v = *(const float4*)(A + (size_t)grow*K + k0 + lc4);
            if (MODE==1) { v.x=gelu_f(v.x); v.y=gelu_f(v.y); v.z=gelu_f(v.z); v.w=gelu_f(v.w); }
            As[lc4+0][row]=v.x; As[lc4+1][row]=v.y; As[lc4+2][row]=v.z; As[lc4+3][row]=v.w;
        }
        #pragma unroll
        for (int rr = 0; rr < 4; rr++) {
            int row = wr + rr*8;
            float4 v = *(const float4*)(W + (size_t)(k0+row)*HID + wc4);
            *(float4*)&Ws[row][wc4] = v;
        }
        __syncthreads();
        #pragma unroll
        for (int kk=0; kk<32; kk++) {
            float4 a  = *(const float4*)&As[kk][row0];
            float4 b0 = *(const float4*)&Ws[kk][col0];
            float4 b1 = *(const float4*)&Ws[kk][col0+4];
            float av[4] = {a.x,a.y,a.z,a.w};
            float bv[8] = {b0.x,b0.y,b0.z,b0.w,b1.x,b1.y,b1.z,b1.w};
            #pragma unroll
            for (int i=0;i<4;i++)
                #pragma unroll
                for (int j=0;j<8;j++) acc[i][j] += av[i]*bv[j];
        }
        __syncthreads();
    }

    float beta = 0.f;
    if (MODE==1) beta = 1.f/(1.f+expf(-skipv[0]));
    #pragma unroll
    for (int i=0;i<4;i++) {
        int grow = block_row + row0 + i;
        if (grow < N) {
            #pragma unroll
            for (int j=0;j<8;j++) {
                float c = acc[i][j] + bias[col0+j];
                if (MODE==1) {
                    float r = res[(size_t)grow*HID + col0 + j];
                    c = beta*c + (1.f-beta)*r;
                }
                Cout[(size_t)grow*HID + col0 + j] = c;
            }
        }
    }
}

// ke[n,h,e'] = sum_d k[n,h,d]*a_rel[h,d,e'] ; ve likewise with m_rel
__global__ __launch_bounds__(512) void rel_transform(
    const float* __restrict__ kin, const float* __restrict__ vin,
    const float* __restrict__ a_rel, const float* __restrict__ m_rel,
    float* __restrict__ keo, float* __restrict__ veo, int N)
{
    __shared__ float Asm[NH*HD*HD];
    __shared__ float Msm[NH*HD*HD];
    __shared__ float kv[4][2][HID];
    int tid = threadIdx.x;
    for (int i=tid;i<NH*HD*HD;i+=512){ Asm[i]=a_rel[i]; Msm[i]=m_rel[i]; }
    int nl = tid >> 7, c = tid & 127;
    int n = blockIdx.x*4 + nl;
    if (n < N) { kv[nl][0][c]=kin[(size_t)n*HID+c]; kv[nl][1][c]=vin[(size_t)n*HID+c]; }
    __syncthreads();
    if (n < N) {
        int h = c >> 4, ep = c & 15;
        float sk=0.f, sv=0.f;
        #pragma unroll
        for (int d=0; d<HD; d++) {
            float kk = kv[nl][0][h*HD+d];
            float vv = kv[nl][1][h*HD+d];
            sk += kk * Asm[(h*HD+d)*HD+ep];
            sv += vv * Msm[(h*HD+d)*HD+ep];
        }
        keo[(size_t)n*HID+c]=sk; veo[(size_t)n*HID+c]=sv;
    }
}

// one wave per destination node; online softmax over CSR neighbors
__global__ __launch_bounds__(256) void attn_edge(
    const float* __restrict__ q, const float* __restrict__ ke,
    const float* __restrict__ ve, const int* __restrict__ off,
    const int* __restrict__ srcs, const float* __restrict__ p_rel,
    float* __restrict__ outp, int Ndst)
{
    int node = blockIdx.x*4 + (threadIdx.x >> 6);
    if (node >= Ndst) return;
    int lane = threadIdx.x & 63;
    int h = lane >> 3, j = lane & 7;
    int base = h*HD + j*2;
    int e0 = off[node], e1 = off[node+1];
    if (e0 == e1) return;
    float2 qv = *(const float2*)(q + (size_t)node*HID + base);
    float pr = p_rel[h] * 0.25f;     // * 1/sqrt(D)
    float m = -INFINITY, s = 0.f;
    float ax = 0.f, ay = 0.f;
    for (int i=e0;i<e1;i++) {
        int src = srcs[i];
        float2 kk = *(const float2*)(ke + (size_t)src*HID + base);
        float2 vv = *(const float2*)(ve + (size_t)src*HID + base);
        float part = qv.x*kk.x + qv.y*kk.y;
        part += __shfl_xor(part, 1);
        part += __shfl_xor(part, 2);
        part += __shfl_xor(part, 4);
        float alpha = part * pr;
        float mn = fmaxf(m, alpha);
        float cc = expf(m - mn);
        float pe = expf(alpha - mn);
        s  = s*cc + pe;
        ax = ax*cc + pe*vv.x;
        ay = ay*cc + pe*vv.y;
        m = mn;
    }
    float inv = 1.f/(s + 1e-16f);
    float* o = outp + (size_t)node*HID + base;
    o[0] += ax*inv;
    o[1] += ay*inv;
}

__global__ void hist_kernel(const int* __restrict__ dst, int E, int* __restrict__ cnt){
    int i = blockIdx.x*256 + threadIdx.x;
    if (i < E) atomicAdd(&cnt[dst[i]], 1);
}

__global__ __launch_bounds__(1024) void scan_kernel(const int* __restrict__ cnt, int* __restrict__ off, int N){
    __shared__ int wsum[16];
    __shared__ int carry_sh;
    int tid=threadIdx.x, lane=tid&63, wid=tid>>6;
    if (tid==0) carry_sh=0;
    __syncthreads();
    for (int base=0; base<N; base+=1024) {
        int i = base+tid;
        int v = (i<N)? cnt[i]:0;
        int sIncl = v;
        #pragma unroll
        for (int ofs=1; ofs<64; ofs<<=1) {
            int t = __shfl_up(sIncl, ofs);
            if (lane >= ofs) sIncl += t;
        }
        if (lane==63) wsum[wid]=sIncl;
        __syncthreads();
        int wofs=0, total=0;
        for (int w=0; w<16; w++){ int wv=wsum[w]; if (w<wid) wofs+=wv; total+=wv; }
        if (i<N) off[i] = carry_sh + wofs + sIncl - v;
        __syncthreads();
        if (tid==0) carry_sh += total;
    }
    __syncthreads();
    if (tid==0) off[N] = carry_sh;
}

__global__ void scatter_kernel(const int* __restrict__ src, const int* __restrict__ dst, int E,
                               const int* __restrict__ off, int* __restrict__ cnt, int* __restrict__ csr){
    int i = blockIdx.x*256 + threadIdx.x;
    if (i < E) {
        int d = dst[i];
        int pos = atomicAdd(&cnt[d], 1);
        csr[off[d]+pos] = src[i];
    }
}

extern "C" void kernel_launch(void* const* d_in, const int* in_sizes, int n_in,
                              void* d_out, int out_size, void* d_ws, size_t ws_size,
                              hipStream_t stream)
{
    const float* xin[3] = {(const float*)d_in[0], (const float*)d_in[1], (const float*)d_in[2]};
    const int FIN[3] = {512, 1024, 128};
    int ns[3];
    for (int t=0;t<3;t++) ns[t] = in_sizes[t]/FIN[t];
    const int* esrc[5]; const int* edst[5]; int E[5];
    for (int e=0;e<5;e++){ esrc[e]=(const int*)d_in[3+2*e]; edst[e]=(const int*)d_in[4+2*e]; E[e]=in_sizes[3+2*e]; }
    const float* Win[3] = {(const float*)d_in[13],(const float*)d_in[15],(const float*)d_in[17]};
    const float* bin[3] = {(const float*)d_in[14],(const float*)d_in[16],(const float*)d_in[18]};
    const float* Wk=(const float*)d_in[19]; const float* Wq=(const float*)d_in[20];
    const float* Wv=(const float*)d_in[21]; const float* Wa=(const float*)d_in[22];
    const float* bk=(const float*)d_in[23]; const float* bq=(const float*)d_in[24];
    const float* bv=(const float*)d_in[25]; const float* ba=(const float*)d_in[26];
    const float* skipp=(const float*)d_in[27];
    const float* a_rel=(const float*)d_in[28];
    const float* m_rel=(const float*)d_in[29];
    const float* p_rel=(const float*)d_in[30];

    static const int ST[5]={2,0,0,1,1}, DT[5]={0,2,1,0,1};

    int NTOT = ns[0]+ns[1]+ns[2];
    int toff[3] = {0, ns[0], ns[0]+ns[1]};
    int maxN = ns[0]; for(int t=1;t<3;t++) if(ns[t]>maxN) maxN=ns[t];

    float* fp = (float*)d_ws;
    float* xsA = fp; fp += (size_t)NTOT*HID;
    float* xsB = fp; fp += (size_t)NTOT*HID;
    float* kb  = fp; fp += (size_t)NTOT*HID;
    float* qb  = fp; fp += (size_t)NTOT*HID;
    float* vb  = fp; fp += (size_t)NTOT*HID;
    float* oacc= fp; fp += (size_t)NTOT*HID;
    float* keb = fp; fp += (size_t)maxN*HID;
    float* veb = fp; fp += (size_t)maxN*HID;
    int* ip = (int*)fp;
    int* off[5]; int* csrc[5];
    for (int e=0;e<5;e++){ off[e]=ip; ip += ns[DT[e]]+1; }
    for (int e=0;e<5;e++){ csrc[e]=ip; ip += E[e]; }
    int* cnt = ip; ip += maxN;

    // ---- CSR build (edges are layer-invariant; build once) ----
    for (int e=0;e<5;e++) {
        int nd = ns[DT[e]];
        hipMemsetAsync(cnt, 0, (size_t)nd*4, stream);
        hist_kernel<<<(E[e]+255)/256,256,0,stream>>>(edst[e], E[e], cnt);
        scan_kernel<<<1,1024,0,stream>>>(cnt, off[e], nd);
        hipMemsetAsync(cnt, 0, (size_t)nd*4, stream);
        scatter_kernel<<<(E[e]+255)/256,256,0,stream>>>(esrc[e], edst[e], E[e], off[e], cnt, csrc[e]);
    }

    // ---- initial projections ----
    for (int t=0;t<3;t++)
        gemm128<0><<<(ns[t]+63)/64,256,0,stream>>>(xin[t], Win[t], bin[t],
            xsA + (size_t)toff[t]*HID, ns[t], FIN[t], nullptr, nullptr);

    float* outp = (float*)d_out;
    for (int l=0;l<2;l++) {
        float* cur = (l==0)? xsA : xsB;
        for (int t=0;t<3;t++) {
            size_t wofs = (size_t)(l*3+t)*HID*HID;
            size_t bofs = (size_t)(l*3+t)*HID;
            const float* a = cur + (size_t)toff[t]*HID;
            gemm128<0><<<(ns[t]+63)/64,256,0,stream>>>(a, Wk+wofs, bk+bofs, kb+(size_t)toff[t]*HID, ns[t], HID, nullptr,nullptr);
            gemm128<0><<<(ns[t]+63)/64,256,0,stream>>>(a, Wq+wofs, bq+bofs, qb+(size_t)toff[t]*HID, ns[t], HID, nullptr,nullptr);
            gemm128<0><<<(ns[t]+63)/64,256,0,stream>>>(a, Wv+wofs, bv+bofs, vb+(size_t)toff[t]*HID, ns[t], HID, nullptr,nullptr);
        }
        hipMemsetAsync(oacc, 0, (size_t)NTOT*HID*4, stream);
        for (int e=0;e<5;e++) {
            int st=ST[e], dt=DT[e];
            size_t relofs = (size_t)(l*5+e)*NH*HD*HD;
            rel_transform<<<(ns[st]+3)/4,512,0,stream>>>(kb+(size_t)toff[st]*HID, vb+(size_t)toff[st]*HID,
                a_rel+relofs, m_rel+relofs, keb, veb, ns[st]);
            attn_edge<<<(ns[dt]+3)/4,256,0,stream>>>(qb+(size_t)toff[dt]*HID, keb, veb, off[e], csrc[e],
                p_rel + (size_t)(l*5+e)*NH, oacc+(size_t)toff[dt]*HID, ns[dt]);
        }
        for (int t=0;t<3;t++) {
            size_t wofs = (size_t)(l*3+t)*HID*HID;
            size_t bofs = (size_t)(l*3+t)*HID;
            float* dest = (l==0)? xsB+(size_t)toff[t]*HID : outp+(size_t)toff[t]*HID;
            gemm128<1><<<(ns[t]+63)/64,256,0,stream>>>(oacc+(size_t)toff[t]*HID, Wa+wofs, ba+bofs, dest,
                ns[t], HID, cur+(size_t)toff[t]*HID, skipp + l*3+t);
        }
    }
}

// Round 3
// 1285.960 us; speedup vs baseline: 1.2022x; 1.2022x over previous
//
#include <hip/hip_runtime.h>
#include <math.h>

#define HID 128
#define NH 8
#define HD 16

typedef __bf16 bf16x8 __attribute__((ext_vector_type(8)));
typedef float f32x4 __attribute__((ext_vector_type(4)));

__device__ __forceinline__ float gelu_f(float x) {
    float x3 = x*x*x;
    return 0.5f*x*(1.f + tanhf(0.7978845608028654f*(x + 0.044715f*x3)));
}

__device__ __forceinline__ unsigned short bf16_rn(float x) {
    unsigned int u = __float_as_uint(x);
    unsigned int r = (u + 0x7FFFu + ((u >> 16) & 1u)) >> 16;
    return (unsigned short)r;
}
__device__ __forceinline__ void split2(float x, unsigned short& h, unsigned short& l) {
    h = bf16_rn(x);
    float hf = __uint_as_float(((unsigned int)h) << 16);
    l = bf16_rn(x - hf);
}

// ---- weight prep: W [K][128] f32 -> Wt hi/lo bf16 [128][K] (col-major of W) ----
__global__ __launch_bounds__(256) void wprep(const float* __restrict__ in,
                                             unsigned short* __restrict__ hi,
                                             unsigned short* __restrict__ lo,
                                             int kbits) {
    int K = 1 << kbits;
    size_t mofs = (size_t)blockIdx.z * ((size_t)K * 128);
    int idx = blockIdx.x * 256 + threadIdx.x;
    if (idx >= K * 128) return;
    int col = idx >> kbits;
    int k = idx & (K - 1);
    float v = in[mofs + (size_t)k * 128 + col];
    unsigned short h, l; split2(v, h, l);
    hi[mofs + idx] = h;  // = col*K + k
    lo[mofs + idx] = l;
}

// ---- MFMA GEMM: C[N x 128*] = op(A[N x K]) @ W + bias ----
// MODE 0: plain. MODE 1: gelu(A) and epilogue out = beta*(C) + (1-beta)*res
struct GemmP {
    const float* A;
    const unsigned short* Wh0; const unsigned short* Wl0;
    const unsigned short* Wh1; const unsigned short* Wl1;
    const unsigned short* Wh2; const unsigned short* Wl2;
    const float* b0; const float* b1; const float* b2;
    float* C0; float* C1; float* C2;
    const float* res; const float* skipv;
    int N; int K;
};

template<int MODE>
__global__ __launch_bounds__(256) void gemm_mfma(GemmP p) {
    __shared__ unsigned short Ah[4096], Al[4096], Bh[4096], Bl[4096];
    const int tid = threadIdx.x;
    const int brow = blockIdx.x * 128;
    const int y = blockIdx.y;
    const unsigned short* Wth = (y == 0) ? p.Wh0 : ((y == 1) ? p.Wh1 : p.Wh2);
    const unsigned short* Wtl = (y == 0) ? p.Wl0 : ((y == 1) ? p.Wl1 : p.Wl2);
    const int K = p.K;
    const int N = p.N;

    f32x4 acc[4][4];
    #pragma unroll
    for (int i = 0; i < 4; i++)
        #pragma unroll
        for (int j = 0; j < 4; j++) acc[i][j] = (f32x4){0.f, 0.f, 0.f, 0.f};

    const int wave = tid >> 6, lane = tid & 63;
    const int wr = wave >> 1, wc = wave & 1;
    const int lrow = lane & 15, lk8 = (lane >> 4) * 8;

    for (int k0 = 0; k0 < K; k0 += 32) {
        // stage A (f32 -> split bf16), layout [128 rows][32 k]
        #pragma unroll
        for (int it = 0; it < 4; it++) {
            int c = tid + it * 256;          // 1024 chunks of 4 floats
            int row = c >> 3, ks = (c & 7) * 4;
            int grow = brow + row; grow = (grow < N) ? grow : (N - 1);
            float4 v = *(const float4*)(p.A + (size_t)grow * K + k0 + ks);
            if (MODE == 1) { v.x = gelu_f(v.x); v.y = gelu_f(v.y); v.z = gelu_f(v.z); v.w = gelu_f(v.w); }
            ushort4 h, l;
            split2(v.x, h.x, l.x); split2(v.y, h.y, l.y);
            split2(v.z, h.z, l.z); split2(v.w, h.w, l.w);
            *(ushort4*)&Ah[row * 32 + ks] = h;
            *(ushort4*)&Al[row * 32 + ks] = l;
        }
        // stage B from pre-split transposed W, layout [128 cols][32 k]
        #pragma unroll
        for (int it = 0; it < 2; it++) {
            int c = tid + it * 256;          // 512 chunks of 8 bf16
            int col = c >> 2, ks = (c & 3) * 8;
            size_t go = (size_t)col * K + k0 + ks;
            *(uint4*)&Bh[col * 32 + ks] = *(const uint4*)(Wth + go);
            *(uint4*)&Bl[col * 32 + ks] = *(const uint4*)(Wtl + go);
        }
        __syncthreads();

        bf16x8 afh[4], afl[4], bfh[4], bfl[4];
        #pragma unroll
        for (int i = 0; i < 4; i++) {
            int oa = (wr * 4 + i) * 512 + lrow * 32 + lk8;
            afh[i] = *(const bf16x8*)&Ah[oa];
            afl[i] = *(const bf16x8*)&Al[oa];
            int ob = (wc * 4 + i) * 512 + lrow * 32 + lk8;
            bfh[i] = *(const bf16x8*)&Bh[ob];
            bfl[i] = *(const bf16x8*)&Bl[ob];
        }
        #pragma unroll
        for (int i = 0; i < 4; i++)
            #pragma unroll
            for (int j = 0; j < 4; j++) {
                acc[i][j] = __builtin_amdgcn_mfma_f32_16x16x32_bf16(afh[i], bfh[j], acc[i][j], 0, 0, 0);
                acc[i][j] = __builtin_amdgcn_mfma_f32_16x16x32_bf16(afh[i], bfl[j], acc[i][j], 0, 0, 0);
                acc[i][j] = __builtin_amdgcn_mfma_f32_16x16x32_bf16(afl[i], bfh[j], acc[i][j], 0, 0, 0);
            }
        __syncthreads();
    }

    const float* bias = (y == 0) ? p.b0 : ((y == 1) ? p.b1 : p.b2);
    float* C = (y == 0) ? p.C0 : ((y == 1) ? p.C1 : p.C2);
    float beta = 0.f;
    if (MODE == 1) beta = 1.f / (1.f + expf(-p.skipv[0]));

    #pragma unroll
    for (int i = 0; i < 4; i++) {
        int rbase = brow + wr * 64 + i * 16 + (lane >> 4) * 4;
        #pragma unroll
        for (int j = 0; j < 4; j++) {
            int col = wc * 64 + j * 16 + lrow;
            float bv = bias[col];
            #pragma unroll
            for (int rr = 0; rr < 4; rr++) {
                int grow = rbase + rr;
                if (grow < N) {
                    float cv = acc[i][j][rr] + bv;
                    if (MODE == 1) {
                        float r = p.res[(size_t)grow * HID + col];
                        cv = beta * cv + (1.f - beta) * r;
                    }
                    C[(size_t)grow * HID + col] = cv;
                }
            }
        }
    }
}

// ---- relation transform: ke[n,h,e'] = sum_d k[n,h,d]*a_rel[h,d,e'] ----
__global__ __launch_bounds__(512) void rel_transform(
    const float* __restrict__ kin, const float* __restrict__ vin,
    const float* __restrict__ a_rel, const float* __restrict__ m_rel,
    float* __restrict__ keo, float* __restrict__ veo, int N)
{
    __shared__ float Asm[NH*HD*HD];
    __shared__ float Msm[NH*HD*HD];
    __shared__ float kv[4][2][HID];
    int tid = threadIdx.x;
    for (int i = tid; i < NH*HD*HD; i += 512) { Asm[i] = a_rel[i]; Msm[i] = m_rel[i]; }
    int nl = tid >> 7, c = tid & 127;
    int n = blockIdx.x * 4 + nl;
    if (n < N) { kv[nl][0][c] = kin[(size_t)n*HID + c]; kv[nl][1][c] = vin[(size_t)n*HID + c]; }
    __syncthreads();
    if (n < N) {
        int h = c >> 4, ep = c & 15;
        float sk = 0.f, sv = 0.f;
        #pragma unroll
        for (int d = 0; d < HD; d++) {
            float kk = kv[nl][0][h*HD + d];
            float vv = kv[nl][1][h*HD + d];
            sk += kk * Asm[(h*HD + d)*HD + ep];
            sv += vv * Msm[(h*HD + d)*HD + ep];
        }
        keo[(size_t)n*HID + c] = sk; veo[(size_t)n*HID + c] = sv;
    }
}

// ---- one wave per destination node; online softmax over CSR neighbors ----
__global__ __launch_bounds__(256) void attn_edge(
    const float* __restrict__ q, const float* __restrict__ ke,
    const float* __restrict__ ve, const int* __restrict__ off,
    const int* __restrict__ srcs, const float* __restrict__ p_rel,
    float* __restrict__ outp, int Ndst)
{
    int node = blockIdx.x * 4 + (threadIdx.x >> 6);
    if (node >= Ndst) return;
    int lane = threadIdx.x & 63;
    int h = lane >> 3, j = lane & 7;
    int base = h * HD + j * 2;
    int e0 = off[node], e1 = off[node + 1];
    if (e0 == e1) return;
    float2 qv = *(const float2*)(q + (size_t)node*HID + base);
    float pr = p_rel[h] * 0.25f;
    float m = -INFINITY, s = 0.f;
    float ax = 0.f, ay = 0.f;
    for (int i = e0; i < e1; i++) {
        int src = srcs[i];
        float2 kk = *(const float2*)(ke + (size_t)src*HID + base);
        float2 vv = *(const float2*)(ve + (size_t)src*HID + base);
        float part = qv.x*kk.x + qv.y*kk.y;
        part += __shfl_xor(part, 1);
        part += __shfl_xor(part, 2);
        part += __shfl_xor(part, 4);
        float alpha = part * pr;
        float mn = fmaxf(m, alpha);
        float cc = expf(m - mn);
        float pe = expf(alpha - mn);
        s  = s*cc + pe;
        ax = ax*cc + pe*vv.x;
        ay = ay*cc + pe*vv.y;
        m = mn;
    }
    float inv = 1.f / (s + 1e-16f);
    float* o = outp + (size_t)node*HID + base;
    o[0] += ax * inv;
    o[1] += ay * inv;
}

// ---- batched CSR build over all 5 edge types ----
struct CsrP {
    const int* esrc[5]; const int* edst[5];
    int* cnt[5]; int* off[5]; int* csr[5]; int* bsum[5];
    int E[5]; int N[5]; int nb[5];
};

__global__ __launch_bounds__(256) void csr_hist(CsrP p) {
    int z = blockIdx.z;
    int i = blockIdx.x * 256 + threadIdx.x;
    if (i < p.E[z]) atomicAdd(&p.cnt[z][p.edst[z][i]], 1);
}

__global__ __launch_bounds__(256) void csr_p1(CsrP p) {
    int z = blockIdx.z, b = blockIdx.x;
    int N = p.N[z];
    if (b * 1024 >= N) return;
    const int* cnt = p.cnt[z];
    __shared__ int wtot[4];
    int tid = threadIdx.x, lane = tid & 63, w = tid >> 6;
    int base = b * 1024 + tid * 4;
    int s = 0;
    #pragma unroll
    for (int k = 0; k < 4; k++) { int i = base + k; if (i < N) s += cnt[i]; }
    int incl = s;
    #pragma unroll
    for (int o = 1; o < 64; o <<= 1) { int t = __shfl_up(incl, o); if (lane >= o) incl += t; }
    if (lane == 63) wtot[w] = incl;
    __syncthreads();
    if (tid == 0) p.bsum[z][b] = wtot[0] + wtot[1] + wtot[2] + wtot[3];
}

__global__ void csr_p2(CsrP p) {
    int z = blockIdx.z;
    if (threadIdx.x == 0) {
        int nb = p.nb[z]; int run = 0; int* bs = p.bsum[z];
        for (int b = 0; b < nb; b++) { int t = bs[b]; bs[b] = run; run += t; }
        p.off[z][p.N[z]] = run;
    }
}

__global__ __launch_bounds__(256) void csr_p3(CsrP p) {
    int z = blockIdx.z, b = blockIdx.x;
    int N = p.N[z];
    if (b * 1024 >= N) return;
    const int* cnt = p.cnt[z]; int* off = p.off[z];
    __shared__ int wtot[4];
    int tid = threadIdx.x, lane = tid & 63, w = tid >> 6;
    int base = b * 1024 + tid * 4;
    int v0=0,v1=0,v2=0,v3=0;
    if (base+0 < N) v0 = cnt[base+0];
    if (base+1 < N) v1 = cnt[base+1];
    if (base+2 < N) v2 = cnt[base+2];
    if (base+3 < N) v3 = cnt[base+3];
    int tsum = v0+v1+v2+v3;
    int incl = tsum;
    #pragma unroll
    for (int o = 1; o < 64; o <<= 1) { int t = __shfl_up(incl, o); if (lane >= o) incl += t; }
    if (lane == 63) wtot[w] = incl;
    __syncthreads();
    int we = 0;
    for (int k = 0; k < w; k++) we += wtot[k];
    int texcl = we + incl - tsum + p.bsum[z][b];
    if (base+0 < N) off[base+0] = texcl;
    if (base+1 < N) off[base+1] = texcl + v0;
    if (base+2 < N) off[base+2] = texcl + v0 + v1;
    if (base+3 < N) off[base+3] = texcl + v0 + v1 + v2;
}

__global__ __launch_bounds__(256) void csr_scatter(CsrP p) {
    int z = blockIdx.z;
    int i = blockIdx.x * 256 + threadIdx.x;
    if (i < p.E[z]) {
        int d = p.edst[z][i];
        int pos = atomicAdd(&p.cnt[z][d], 1);
        p.csr[z][p.off[z][d] + pos] = p.esrc[z][i];
    }
}

extern "C" void kernel_launch(void* const* d_in, const int* in_sizes, int n_in,
                              void* d_out, int out_size, void* d_ws, size_t ws_size,
                              hipStream_t stream)
{
    const float* xin[3] = {(const float*)d_in[0], (const float*)d_in[1], (const float*)d_in[2]};
    const int FIN[3] = {512, 1024, 128};
    const int KBITS[3] = {9, 10, 7};
    int ns[3];
    for (int t = 0; t < 3; t++) ns[t] = in_sizes[t] / FIN[t];
    const int* esrc[5]; const int* edst[5]; int E[5];
    for (int e = 0; e < 5; e++) { esrc[e] = (const int*)d_in[3+2*e]; edst[e] = (const int*)d_in[4+2*e]; E[e] = in_sizes[3+2*e]; }
    const float* Win[3] = {(const float*)d_in[13], (const float*)d_in[15], (const float*)d_in[17]};
    const float* bin[3] = {(const float*)d_in[14], (const float*)d_in[16], (const float*)d_in[18]};
    const float* Wk = (const float*)d_in[19]; const float* Wq = (const float*)d_in[20];
    const float* Wv = (const float*)d_in[21]; const float* Wa = (const float*)d_in[22];
    const float* bk = (const float*)d_in[23]; const float* bq = (const float*)d_in[24];
    const float* bv = (const float*)d_in[25]; const float* ba = (const float*)d_in[26];
    const float* skipp = (const float*)d_in[27];
    const float* a_rel = (const float*)d_in[28];
    const float* m_rel = (const float*)d_in[29];
    const float* p_rel = (const float*)d_in[30];

    static const int ST[5] = {2,0,0,1,1}, DT[5] = {0,2,1,0,1};

    int NTOT = ns[0] + ns[1] + ns[2];
    int toff[3] = {0, ns[0], ns[0] + ns[1]};
    int maxN = ns[0]; for (int t = 1; t < 3; t++) if (ns[t] > maxN) maxN = ns[t];
    int maxE = E[0]; for (int e = 1; e < 5; e++) if (E[e] > maxE) maxE = E[e];

    // ---- workspace carve ----
    float* fp = (float*)d_ws;
    float* xsA = fp; fp += (size_t)NTOT*HID;
    float* xsB = fp; fp += (size_t)NTOT*HID;
    float* kb  = fp; fp += (size_t)NTOT*HID;
    float* qb  = fp; fp += (size_t)NTOT*HID;
    float* vb  = fp; fp += (size_t)NTOT*HID;
    float* oacc= fp; fp += (size_t)NTOT*HID;
    float* keb = fp; fp += (size_t)maxN*HID;
    float* veb = fp; fp += (size_t)maxN*HID;
    // bf16 split weights
    unsigned short* up = (unsigned short*)fp;
    unsigned short* wprojh[3]; unsigned short* wprojl[3];
    for (int t = 0; t < 3; t++) { wprojh[t] = up; up += (size_t)FIN[t]*HID; wprojl[t] = up; up += (size_t)FIN[t]*HID; }
    unsigned short* wkh = up; up += 6*HID*HID; unsigned short* wkl = up; up += 6*HID*HID;
    unsigned short* wqh = up; up += 6*HID*HID; unsigned short* wql = up; up += 6*HID*HID;
    unsigned short* wvh = up; up += 6*HID*HID; unsigned short* wvl = up; up += 6*HID*HID;
    unsigned short* wah = up; up += 6*HID*HID; unsigned short* wal = up; up += 6*HID*HID;
    // int region
    uintptr_t ip_ = ((uintptr_t)up + 255) & ~(uintptr_t)255;
    int* ip = (int*)ip_;
    int* off[5]; int* csrc[5]; int* cntp[5]; int* bsump[5];
    for (int e = 0; e < 5; e++) { off[e] = ip; ip += ns[DT[e]] + 1; }
    for (int e = 0; e < 5; e++) { csrc[e] = ip; ip += E[e]; }
    int* cntbase = ip; int cnt_tot = 0;
    for (int e = 0; e < 5; e++) { cntp[e] = cntbase + cnt_tot; cnt_tot += ns[DT[e]]; }
    ip += cnt_tot;
    for (int e = 0; e < 5; e++) { bsump[e] = ip; ip += 64; }

    // ---- weight prep ----
    for (int t = 0; t < 3; t++) {
        int total = FIN[t] * HID;
        wprep<<<dim3((total+255)/256, 1, 1), 256, 0, stream>>>(Win[t], wprojh[t], wprojl[t], KBITS[t]);
    }
    wprep<<<dim3(64, 1, 6), 256, 0, stream>>>(Wk, wkh, wkl, 7);
    wprep<<<dim3(64, 1, 6), 256, 0, stream>>>(Wq, wqh, wql, 7);
    wprep<<<dim3(64, 1, 6), 256, 0, stream>>>(Wv, wvh, wvl, 7);
    wprep<<<dim3(64, 1, 6), 256, 0, stream>>>(Wa, wah, wal, 7);

    // ---- CSR build ----
    CsrP cp;
    for (int e = 0; e < 5; e++) {
        cp.esrc[e] = esrc[e]; cp.edst[e] = edst[e];
        cp.cnt[e] = cntp[e]; cp.off[e] = off[e]; cp.csr[e] = csrc[e]; cp.bsum[e] = bsump[e];
        cp.E[e] = E[e]; cp.N[e] = ns[DT[e]]; cp.nb[e] = (ns[DT[e]] + 1023) / 1024;
    }
    int nbmax = (maxN + 1023) / 1024;
    hipMemsetAsync(cntbase, 0, (size_t)cnt_tot * 4, stream);
    csr_hist<<<dim3((maxE+255)/256, 1, 5), 256, 0, stream>>>(cp);
    csr_p1<<<dim3(nbmax, 1, 5), 256, 0, stream>>>(cp);
    csr_p2<<<dim3(1, 1, 5), 64, 0, stream>>>(cp);
    csr_p3<<<dim3(nbmax, 1, 5), 256, 0, stream>>>(cp);
    hipMemsetAsync(cntbase, 0, (size_t)cnt_tot * 4, stream);
    csr_scatter<<<dim3((maxE+255)/256, 1, 5), 256, 0, stream>>>(cp);

    // ---- initial projections ----
    for (int t = 0; t < 3; t++) {
        GemmP g = {};
        g.A = xin[t]; g.Wh0 = wprojh[t]; g.Wl0 = wprojl[t];
        g.b0 = bin[t]; g.C0 = xsA + (size_t)toff[t]*HID;
        g.N = ns[t]; g.K = FIN[t];
        gemm_mfma<0><<<dim3((ns[t]+127)/128, 1), 256, 0, stream>>>(g);
    }

    float* outp = (float*)d_out;
    for (int l = 0; l < 2; l++) {
        float* cur = (l == 0) ? xsA : xsB;
        // fused KQV per type (grid.y = 3)
        for (int t = 0; t < 3; t++) {
            int m = l*3 + t;
            GemmP g = {};
            g.A = cur + (size_t)toff[t]*HID;
            g.Wh0 = wkh + (size_t)m*HID*HID; g.Wl0 = wkl + (size_t)m*HID*HID;
            g.Wh1 = wqh + (size_t)m*HID*HID; g.Wl1 = wql + (size_t)m*HID*HID;
            g.Wh2 = wvh + (size_t)m*HID*HID; g.Wl2 = wvl + (size_t)m*HID*HID;
            g.b0 = bk + (size_t)m*HID; g.b1 = bq + (size_t)m*HID; g.b2 = bv + (size_t)m*HID;
            g.C0 = kb + (size_t)toff[t]*HID; g.C1 = qb + (size_t)toff[t]*HID; g.C2 = vb + (size_t)toff[t]*HID;
            g.N = ns[t]; g.K = HID;
            gemm_mfma<0><<<dim3((ns[t]+127)/128, 3), 256, 0, stream>>>(g);
        }
        hipMemsetAsync(oacc, 0, (size_t)NTOT*HID*4, stream);
        for (int e = 0; e < 5; e++) {
            int st = ST[e], dt = DT[e];
            size_t relofs = (size_t)(l*5 + e)*NH*HD*HD;
            rel_transform<<<(ns[st]+3)/4, 512, 0, stream>>>(kb + (size_t)toff[st]*HID, vb + (size_t)toff[st]*HID,
                a_rel + relofs, m_rel + relofs, keb, veb, ns[st]);
            attn_edge<<<(ns[dt]+3)/4, 256, 0, stream>>>(qb + (size_t)toff[dt]*HID, keb, veb, off[e], csrc[e],
                p_rel + (size_t)(l*5 + e)*NH, oacc + (size_t)toff[dt]*HID, ns[dt]);
        }
        // epilogue GEMM with fused gelu + skip
        for (int t = 0; t < 3; t++) {
            int m = l*3 + t;
            GemmP g = {};
            g.A = oacc + (size_t)toff[t]*HID;
            g.Wh0 = wah + (size_t)m*HID*HID; g.Wl0 = wal + (size_t)m*HID*HID;
            g.b0 = ba + (size_t)m*HID;
            g.C0 = ((l == 0) ? xsB : outp) + (size_t)toff[t]*HID;
            g.res = cur + (size_t)toff[t]*HID;
            g.skipv = skipp + l*3 + t;
            g.N = ns[t]; g.K = HID;
            gemm_mfma<1><<<dim3((ns[t]+127)/128, 1), 256, 0, stream>>>(g);
        }
    }
}

// Round 4
// 1017.114 us; speedup vs baseline: 1.5199x; 1.2643x over previous
//
#include <hip/hip_runtime.h>
#include <math.h>

#define HID 128
#define NH 8
#define HD 16

typedef __bf16 bf16x8 __attribute__((ext_vector_type(8)));
typedef float f32x4 __attribute__((ext_vector_type(4)));

__device__ __forceinline__ float gelu_f(float x) {
    float x3 = x*x*x;
    return 0.5f*x*(1.f + tanhf(0.7978845608028654f*(x + 0.044715f*x3)));
}

__device__ __forceinline__ unsigned short bf16_rn(float x) {
    unsigned int u = __float_as_uint(x);
    unsigned int r = (u + 0x7FFFu + ((u >> 16) & 1u)) >> 16;
    return (unsigned short)r;
}
__device__ __forceinline__ void split2(float x, unsigned short& h, unsigned short& l) {
    h = bf16_rn(x);
    float hf = __uint_as_float(((unsigned int)h) << 16);
    l = bf16_rn(x - hf);
}

// ---- weight prep: W [K][128] f32 -> hi/lo bf16 [128 cols][K] ----
__global__ __launch_bounds__(256) void wprep(const float* __restrict__ in,
                                             unsigned short* __restrict__ hi,
                                             unsigned short* __restrict__ lo,
                                             int kbits) {
    int K = 1 << kbits;
    size_t mofs = (size_t)blockIdx.z * ((size_t)K * 128);
    int idx = blockIdx.x * 256 + threadIdx.x;
    if (idx >= K * 128) return;
    int col = idx >> kbits;
    int k = idx & (K - 1);
    float v = in[mofs + (size_t)k * 128 + col];
    unsigned short h, l; split2(v, h, l);
    hi[mofs + idx] = h;
    lo[mofs + idx] = l;
}

// ---- fused relation weights: out[m][col=h*16+e'][c] = sum_d W[l,st,c,h*16+d]*rel[m,h,d,e'] ----
__global__ __launch_bounds__(256) void fuse_w(const float* __restrict__ W,
                                              const float* __restrict__ rel,
                                              unsigned short* __restrict__ oh,
                                              unsigned short* __restrict__ ol) {
    const int STm[5] = {2,0,0,1,1};
    int m = blockIdx.y; int l = m / 5, e = m % 5; int st = STm[e];
    int idx = blockIdx.x * 256 + threadIdx.x;   // 0..16383
    int col = idx >> 7, c = idx & 127;
    int h = col >> 4, ep = col & 15;
    const float* w = W + (size_t)(l*3 + st) * 16384;
    const float* r = rel + (size_t)m * 2048 + h * 256;
    float s = 0.f;
    #pragma unroll
    for (int d = 0; d < 16; d++) s += w[c * 128 + h * 16 + d] * r[d * 16 + ep];
    unsigned short hh, ll; split2(s, hh, ll);
    oh[(size_t)m * 16384 + idx] = hh;
    ol[(size_t)m * 16384 + idx] = ll;
}

__global__ void fuse_b(const float* __restrict__ b, const float* __restrict__ rel,
                       float* __restrict__ ob) {
    const int STm[5] = {2,0,0,1,1};
    int m = blockIdx.y; int l = m / 5, e = m % 5; int st = STm[e];
    int col = threadIdx.x;
    int h = col >> 4, ep = col & 15;
    const float* bb = b + (l*3 + st) * 128;
    const float* r = rel + (size_t)m * 2048 + h * 256;
    float s = 0.f;
    #pragma unroll
    for (int d = 0; d < 16; d++) s += bb[h * 16 + d] * r[d * 16 + ep];
    ob[m * 128 + col] = s;
}

// ---- activation pre-split: f32 -> hi/lo bf16, optional gelu ----
__global__ __launch_bounds__(256) void presplit(const float* __restrict__ in,
                                                unsigned short* __restrict__ hi,
                                                unsigned short* __restrict__ lo,
                                                int n4, int do_gelu) {
    int i = blockIdx.x * 256 + threadIdx.x;
    if (i >= n4) return;
    float4 v = ((const float4*)in)[i];
    if (do_gelu) { v.x = gelu_f(v.x); v.y = gelu_f(v.y); v.z = gelu_f(v.z); v.w = gelu_f(v.w); }
    ushort4 h, l;
    split2(v.x, h.x, l.x); split2(v.y, h.y, l.y);
    split2(v.z, h.z, l.z); split2(v.w, h.w, l.w);
    ((ushort4*)hi)[i] = h; ((ushort4*)lo)[i] = l;
}

// ---- job-table GEMM, K=128 fixed, A pre-split ----
struct Job {
    const unsigned short* Ah; const unsigned short* Al;
    const unsigned short* Wh; const unsigned short* Wl;
    const float* bias; const float* res; const float* skipv;
    float* C;
    int N; int mode;
};
struct Jobs { Job j[13]; };

#define LDP 40   // padded row length in shorts (80B -> bank stride 20, 2-way = free)

__global__ __launch_bounds__(256) void gemm_ws(Jobs js) {
    const Job jb = js.j[blockIdx.y];
    const int brow = blockIdx.x * 128;
    if (brow >= jb.N) return;
    __shared__ unsigned short Ah[128*LDP], Al[128*LDP], Bh[128*LDP], Bl[128*LDP];
    const int tid = threadIdx.x;
    const int wave = tid >> 6, lane = tid & 63;
    const int wr = wave >> 1, wc = wave & 1;
    const int lrow = lane & 15, lk8 = (lane >> 4) * 8;
    const int N = jb.N;

    f32x4 acc[4][4];
    #pragma unroll
    for (int i = 0; i < 4; i++)
        #pragma unroll
        for (int j = 0; j < 4; j++) acc[i][j] = (f32x4){0.f,0.f,0.f,0.f};

    for (int k0 = 0; k0 < 128; k0 += 32) {
        #pragma unroll
        for (int it = 0; it < 2; it++) {
            int c = tid + it * 256;          // 512 chunks of 8 shorts
            int row = c >> 2, ks = (c & 3) * 8;
            int ar = brow + row; ar = (ar < N) ? ar : (N - 1);
            size_t ga = (size_t)ar * 128 + k0 + ks;
            size_t gb = (size_t)row * 128 + k0 + ks;
            *(uint4*)&Ah[row*LDP + ks] = *(const uint4*)(jb.Ah + ga);
            *(uint4*)&Al[row*LDP + ks] = *(const uint4*)(jb.Al + ga);
            *(uint4*)&Bh[row*LDP + ks] = *(const uint4*)(jb.Wh + gb);
            *(uint4*)&Bl[row*LDP + ks] = *(const uint4*)(jb.Wl + gb);
        }
        __syncthreads();
        bf16x8 afh[4], afl[4], bfh[4], bfl[4];
        #pragma unroll
        for (int i = 0; i < 4; i++) {
            int oa = (wr*64 + i*16 + lrow) * LDP + lk8;
            afh[i] = *(const bf16x8*)&Ah[oa];
            afl[i] = *(const bf16x8*)&Al[oa];
            int ob = (wc*64 + i*16 + lrow) * LDP + lk8;
            bfh[i] = *(const bf16x8*)&Bh[ob];
            bfl[i] = *(const bf16x8*)&Bl[ob];
        }
        #pragma unroll
        for (int i = 0; i < 4; i++)
            #pragma unroll
            for (int j = 0; j < 4; j++) {
                acc[i][j] = __builtin_amdgcn_mfma_f32_16x16x32_bf16(afh[i], bfh[j], acc[i][j], 0, 0, 0);
                acc[i][j] = __builtin_amdgcn_mfma_f32_16x16x32_bf16(afh[i], bfl[j], acc[i][j], 0, 0, 0);
                acc[i][j] = __builtin_amdgcn_mfma_f32_16x16x32_bf16(afl[i], bfh[j], acc[i][j], 0, 0, 0);
            }
        __syncthreads();
    }

    float beta = 0.f;
    if (jb.mode == 1) beta = 1.f / (1.f + expf(-jb.skipv[0]));
    #pragma unroll
    for (int i = 0; i < 4; i++) {
        int rbase = brow + wr*64 + i*16 + (lane >> 4) * 4;
        #pragma unroll
        for (int j = 0; j < 4; j++) {
            int col = wc*64 + j*16 + lrow;
            float bv = jb.bias[col];
            #pragma unroll
            for (int rr = 0; rr < 4; rr++) {
                int grow = rbase + rr;
                if (grow < N) {
                    float cv = acc[i][j][rr] + bv;
                    if (jb.mode == 1) {
                        float r = jb.res[(size_t)grow * 128 + col];
                        cv = beta * cv + (1.f - beta) * r;
                    }
                    jb.C[(size_t)grow * 128 + col] = cv;
                }
            }
        }
    }
}

// ---- init projection GEMM: A f32 [N x K], split on the fly ----
__global__ __launch_bounds__(256) void gemm_init(const float* __restrict__ A,
        const unsigned short* __restrict__ Wth, const unsigned short* __restrict__ Wtl,
        const float* __restrict__ bias, float* __restrict__ C, int N, int K) {
    __shared__ unsigned short Ah[128*LDP], Al[128*LDP], Bh[128*LDP], Bl[128*LDP];
    const int tid = threadIdx.x;
    const int brow = blockIdx.x * 128;
    if (brow >= N) return;
    const int wave = tid >> 6, lane = tid & 63;
    const int wr = wave >> 1, wc = wave & 1;
    const int lrow = lane & 15, lk8 = (lane >> 4) * 8;

    f32x4 acc[4][4];
    #pragma unroll
    for (int i = 0; i < 4; i++)
        #pragma unroll
        for (int j = 0; j < 4; j++) acc[i][j] = (f32x4){0.f,0.f,0.f,0.f};

    for (int k0 = 0; k0 < K; k0 += 32) {
        #pragma unroll
        for (int it = 0; it < 4; it++) {
            int c = tid + it * 256;          // 1024 chunks of 4 floats
            int row = c >> 3, ks = (c & 7) * 4;
            int grow = brow + row; grow = (grow < N) ? grow : (N - 1);
            float4 v = *(const float4*)(A + (size_t)grow * K + k0 + ks);
            ushort4 h, l;
            split2(v.x, h.x, l.x); split2(v.y, h.y, l.y);
            split2(v.z, h.z, l.z); split2(v.w, h.w, l.w);
            *(ushort4*)&Ah[row*LDP + ks] = h;
            *(ushort4*)&Al[row*LDP + ks] = l;
        }
        #pragma unroll
        for (int it = 0; it < 2; it++) {
            int c = tid + it * 256;          // 512 chunks of 8 shorts
            int col = c >> 2, ks = (c & 3) * 8;
            size_t go = (size_t)col * K + k0 + ks;
            *(uint4*)&Bh[col*LDP + ks] = *(const uint4*)(Wth + go);
            *(uint4*)&Bl[col*LDP + ks] = *(const uint4*)(Wtl + go);
        }
        __syncthreads();
        bf16x8 afh[4], afl[4], bfh[4], bfl[4];
        #pragma unroll
        for (int i = 0; i < 4; i++) {
            int oa = (wr*64 + i*16 + lrow) * LDP + lk8;
            afh[i] = *(const bf16x8*)&Ah[oa];
            afl[i] = *(const bf16x8*)&Al[oa];
            int ob = (wc*64 + i*16 + lrow) * LDP + lk8;
            bfh[i] = *(const bf16x8*)&Bh[ob];
            bfl[i] = *(const bf16x8*)&Bl[ob];
        }
        #pragma unroll
        for (int i = 0; i < 4; i++)
            #pragma unroll
            for (int j = 0; j < 4; j++) {
                acc[i][j] = __builtin_amdgcn_mfma_f32_16x16x32_bf16(afh[i], bfh[j], acc[i][j], 0, 0, 0);
                acc[i][j] = __builtin_amdgcn_mfma_f32_16x16x32_bf16(afh[i], bfl[j], acc[i][j], 0, 0, 0);
                acc[i][j] = __builtin_amdgcn_mfma_f32_16x16x32_bf16(afl[i], bfh[j], acc[i][j], 0, 0, 0);
            }
        __syncthreads();
    }

    #pragma unroll
    for (int i = 0; i < 4; i++) {
        int rbase = brow + wr*64 + i*16 + (lane >> 4) * 4;
        #pragma unroll
        for (int j = 0; j < 4; j++) {
            int col = wc*64 + j*16 + lrow;
            float bv = bias[col];
            #pragma unroll
            for (int rr = 0; rr < 4; rr++) {
                int grow = rbase + rr;
                if (grow < N) C[(size_t)grow * 128 + col] = acc[i][j][rr] + bv;
            }
        }
    }
}

// ---- one wave per destination node; online softmax over CSR neighbors ----
__global__ __launch_bounds__(256) void attn_edge(
    const float* __restrict__ q, const float* __restrict__ ke,
    const float* __restrict__ ve, const int* __restrict__ off,
    const int* __restrict__ srcs, const float* __restrict__ p_rel,
    float* __restrict__ outp, int Ndst)
{
    int node = blockIdx.x * 4 + (threadIdx.x >> 6);
    if (node >= Ndst) return;
    int lane = threadIdx.x & 63;
    int h = lane >> 3, j = lane & 7;
    int base = h * HD + j * 2;
    int e0 = off[node], e1 = off[node + 1];
    if (e0 == e1) return;
    float2 qv = *(const float2*)(q + (size_t)node*HID + base);
    float pr = p_rel[h] * 0.25f;
    float m = -INFINITY, s = 0.f;
    float ax = 0.f, ay = 0.f;
    for (int i = e0; i < e1; i++) {
        int src = srcs[i];
        float2 kk = *(const float2*)(ke + (size_t)src*HID + base);
        float2 vv = *(const float2*)(ve + (size_t)src*HID + base);
        float part = qv.x*kk.x + qv.y*kk.y;
        part += __shfl_xor(part, 1);
        part += __shfl_xor(part, 2);
        part += __shfl_xor(part, 4);
        float alpha = part * pr;
        float mn = fmaxf(m, alpha);
        float cc = expf(m - mn);
        float pe = expf(alpha - mn);
        s  = s*cc + pe;
        ax = ax*cc + pe*vv.x;
        ay = ay*cc + pe*vv.y;
        m = mn;
    }
    float inv = 1.f / (s + 1e-16f);
    float* o = outp + (size_t)node*HID + base;
    o[0] += ax * inv;
    o[1] += ay * inv;
}

// ---- batched CSR build over all 5 edge types ----
struct CsrP {
    const int* esrc[5]; const int* edst[5];
    int* cnt[5]; int* off[5]; int* csr[5]; int* bsum[5];
    int E[5]; int N[5]; int nb[5];
};

__global__ __launch_bounds__(256) void csr_hist(CsrP p) {
    int z = blockIdx.z;
    int i = blockIdx.x * 256 + threadIdx.x;
    if (i < p.E[z]) atomicAdd(&p.cnt[z][p.edst[z][i]], 1);
}

__global__ __launch_bounds__(256) void csr_p1(CsrP p) {
    int z = blockIdx.z, b = blockIdx.x;
    int N = p.N[z];
    if (b * 1024 >= N) return;
    const int* cnt = p.cnt[z];
    __shared__ int wtot[4];
    int tid = threadIdx.x, lane = tid & 63, w = tid >> 6;
    int base = b * 1024 + tid * 4;
    int s = 0;
    #pragma unroll
    for (int k = 0; k < 4; k++) { int i = base + k; if (i < N) s += cnt[i]; }
    int incl = s;
    #pragma unroll
    for (int o = 1; o < 64; o <<= 1) { int t = __shfl_up(incl, o); if (lane >= o) incl += t; }
    if (lane == 63) wtot[w] = incl;
    __syncthreads();
    if (tid == 0) p.bsum[z][b] = wtot[0] + wtot[1] + wtot[2] + wtot[3];
}

__global__ void csr_p2(CsrP p) {
    int z = blockIdx.z;
    if (threadIdx.x == 0) {
        int nb = p.nb[z]; int run = 0; int* bs = p.bsum[z];
        for (int b = 0; b < nb; b++) { int t = bs[b]; bs[b] = run; run += t; }
        p.off[z][p.N[z]] = run;
    }
}

__global__ __launch_bounds__(256) void csr_p3(CsrP p) {
    int z = blockIdx.z, b = blockIdx.x;
    int N = p.N[z];
    if (b * 1024 >= N) return;
    const int* cnt = p.cnt[z]; int* off = p.off[z];
    __shared__ int wtot[4];
    int tid = threadIdx.x, lane = tid & 63, w = tid >> 6;
    int base = b * 1024 + tid * 4;
    int v0=0,v1=0,v2=0,v3=0;
    if (base+0 < N) v0 = cnt[base+0];
    if (base+1 < N) v1 = cnt[base+1];
    if (base+2 < N) v2 = cnt[base+2];
    if (base+3 < N) v3 = cnt[base+3];
    int tsum = v0+v1+v2+v3;
    int incl = tsum;
    #pragma unroll
    for (int o = 1; o < 64; o <<= 1) { int t = __shfl_up(incl, o); if (lane >= o) incl += t; }
    if (lane == 63) wtot[w] = incl;
    __syncthreads();
    int we = 0;
    for (int k = 0; k < w; k++) we += wtot[k];
    int texcl = we + incl - tsum + p.bsum[z][b];
    if (base+0 < N) off[base+0] = texcl;
    if (base+1 < N) off[base+1] = texcl + v0;
    if (base+2 < N) off[base+2] = texcl + v0 + v1;
    if (base+3 < N) off[base+3] = texcl + v0 + v1 + v2;
}

__global__ __launch_bounds__(256) void csr_scatter(CsrP p) {
    int z = blockIdx.z;
    int i = blockIdx.x * 256 + threadIdx.x;
    if (i < p.E[z]) {
        int d = p.edst[z][i];
        int pos = atomicAdd(&p.cnt[z][d], 1);
        p.csr[z][p.off[z][d] + pos] = p.esrc[z][i];
    }
}

extern "C" void kernel_launch(void* const* d_in, const int* in_sizes, int n_in,
                              void* d_out, int out_size, void* d_ws, size_t ws_size,
                              hipStream_t stream)
{
    const float* xin[3] = {(const float*)d_in[0], (const float*)d_in[1], (const float*)d_in[2]};
    const int FIN[3] = {512, 1024, 128};
    const int KBITS[3] = {9, 10, 7};
    int ns[3];
    for (int t = 0; t < 3; t++) ns[t] = in_sizes[t] / FIN[t];
    const int* esrc[5]; const int* edst[5]; int E[5];
    for (int e = 0; e < 5; e++) { esrc[e] = (const int*)d_in[3+2*e]; edst[e] = (const int*)d_in[4+2*e]; E[e] = in_sizes[3+2*e]; }
    const float* Win[3] = {(const float*)d_in[13], (const float*)d_in[15], (const float*)d_in[17]};
    const float* bin[3] = {(const float*)d_in[14], (const float*)d_in[16], (const float*)d_in[18]};
    const float* Wk = (const float*)d_in[19]; const float* Wq = (const float*)d_in[20];
    const float* Wv = (const float*)d_in[21]; const float* Wa = (const float*)d_in[22];
    const float* bk = (const float*)d_in[23]; const float* bq = (const float*)d_in[24];
    const float* bv = (const float*)d_in[25]; const float* ba = (const float*)d_in[26];
    const float* skipp = (const float*)d_in[27];
    const float* a_rel = (const float*)d_in[28];
    const float* m_rel = (const float*)d_in[29];
    const float* p_rel = (const float*)d_in[30];

    static const int ST[5] = {2,0,0,1,1}, DT[5] = {0,2,1,0,1};

    int NTOT = ns[0] + ns[1] + ns[2];
    int toff[3] = {0, ns[0], ns[0] + ns[1]};
    int maxN = ns[0]; for (int t = 1; t < 3; t++) if (ns[t] > maxN) maxN = ns[t];
    int maxE = E[0]; for (int e = 1; e < 5; e++) if (E[e] > maxE) maxE = E[e];

    // ---- workspace carve ----
    float* fp = (float*)d_ws;
    float* xsA = fp; fp += (size_t)NTOT*HID;
    float* xsB = fp; fp += (size_t)NTOT*HID;
    float* qb  = fp; fp += (size_t)NTOT*HID;
    float* oacc= fp; fp += (size_t)NTOT*HID;
    float* keb[5]; float* veb[5];
    for (int e = 0; e < 5; e++) {
        keb[e] = fp; fp += (size_t)ns[ST[e]]*HID;
        veb[e] = fp; fp += (size_t)ns[ST[e]]*HID;
    }
    float* bke = fp; fp += 10*128;   // fused ke biases
    float* bve = fp; fp += 10*128;   // fused ve biases
    // shorts
    unsigned short* up = (unsigned short*)fp;
    unsigned short* xh = up; up += (size_t)NTOT*HID;
    unsigned short* xl = up; up += (size_t)NTOT*HID;
    unsigned short* wih[3]; unsigned short* wil[3];
    for (int t = 0; t < 3; t++) { wih[t] = up; up += (size_t)FIN[t]*HID; wil[t] = up; up += (size_t)FIN[t]*HID; }
    unsigned short* wqh = up; up += 6*16384; unsigned short* wql = up; up += 6*16384;
    unsigned short* wah = up; up += 6*16384; unsigned short* wal = up; up += 6*16384;
    unsigned short* wkeh = up; up += 10*16384; unsigned short* wkel = up; up += 10*16384;
    unsigned short* wveh = up; up += 10*16384; unsigned short* wvel = up; up += 10*16384;
    // ints
    uintptr_t ip_ = ((uintptr_t)up + 255) & ~(uintptr_t)255;
    int* ip = (int*)ip_;
    int* off[5]; int* csrc[5]; int* cntp[5]; int* bsump[5];
    for (int e = 0; e < 5; e++) { off[e] = ip; ip += ns[DT[e]] + 1; }
    for (int e = 0; e < 5; e++) { csrc[e] = ip; ip += E[e]; }
    int* cntbase = ip; int cnt_tot = 0;
    for (int e = 0; e < 5; e++) { cntp[e] = cntbase + cnt_tot; cnt_tot += ns[DT[e]]; }
    ip += cnt_tot;
    for (int e = 0; e < 5; e++) { bsump[e] = ip; ip += 64; }

    // ---- weight prep ----
    for (int t = 0; t < 3; t++)
        wprep<<<dim3((FIN[t]*HID+255)/256, 1, 1), 256, 0, stream>>>(Win[t], wih[t], wil[t], KBITS[t]);
    wprep<<<dim3(64, 1, 6), 256, 0, stream>>>(Wq, wqh, wql, 7);
    wprep<<<dim3(64, 1, 6), 256, 0, stream>>>(Wa, wah, wal, 7);
    fuse_w<<<dim3(64, 10), 256, 0, stream>>>(Wk, a_rel, wkeh, wkel);
    fuse_w<<<dim3(64, 10), 256, 0, stream>>>(Wv, m_rel, wveh, wvel);
    fuse_b<<<dim3(1, 10), 128, 0, stream>>>(bk, a_rel, bke);
    fuse_b<<<dim3(1, 10), 128, 0, stream>>>(bv, m_rel, bve);

    // ---- CSR build ----
    CsrP cp;
    for (int e = 0; e < 5; e++) {
        cp.esrc[e] = esrc[e]; cp.edst[e] = edst[e];
        cp.cnt[e] = cntp[e]; cp.off[e] = off[e]; cp.csr[e] = csrc[e]; cp.bsum[e] = bsump[e];
        cp.E[e] = E[e]; cp.N[e] = ns[DT[e]]; cp.nb[e] = (ns[DT[e]] + 1023) / 1024;
    }
    int nbmax = (maxN + 1023) / 1024;
    hipMemsetAsync(cntbase, 0, (size_t)cnt_tot * 4, stream);
    csr_hist<<<dim3((maxE+255)/256, 1, 5), 256, 0, stream>>>(cp);
    csr_p1<<<dim3(nbmax, 1, 5), 256, 0, stream>>>(cp);
    csr_p2<<<dim3(1, 1, 5), 64, 0, stream>>>(cp);
    csr_p3<<<dim3(nbmax, 1, 5), 256, 0, stream>>>(cp);
    hipMemsetAsync(cntbase, 0, (size_t)cnt_tot * 4, stream);
    csr_scatter<<<dim3((maxE+255)/256, 1, 5), 256, 0, stream>>>(cp);

    // ---- initial projections ----
    for (int t = 0; t < 3; t++)
        gemm_init<<<(ns[t]+127)/128, 256, 0, stream>>>(xin[t], wih[t], wil[t], bin[t],
            xsA + (size_t)toff[t]*HID, ns[t], FIN[t]);

    float* outp = (float*)d_out;
    int n4 = NTOT * HID / 4;
    int gx = (maxN + 127) / 128;

    for (int l = 0; l < 2; l++) {
        float* cur = (l == 0) ? xsA : xsB;

        // pre-split activations
        presplit<<<(n4+255)/256, 256, 0, stream>>>(cur, xh, xl, n4, 0);

        // wide GEMM: q + ke/ve for all relations, one dispatch
        Jobs js = {};
        int ji = 0;
        for (int t = 0; t < 3; t++) {
            int m = l*3 + t;
            // q
            js.j[ji++] = { xh + (size_t)toff[t]*HID, xl + (size_t)toff[t]*HID,
                           wqh + (size_t)m*16384, wql + (size_t)m*16384,
                           bq + (size_t)m*HID, nullptr, nullptr,
                           qb + (size_t)toff[t]*HID, ns[t], 0 };
            // relations with src type t
            for (int e = 0; e < 5; e++) {
                if (ST[e] != t) continue;
                int mm = l*5 + e;
                js.j[ji++] = { xh + (size_t)toff[t]*HID, xl + (size_t)toff[t]*HID,
                               wkeh + (size_t)mm*16384, wkel + (size_t)mm*16384,
                               bke + mm*128, nullptr, nullptr,
                               keb[e], ns[t], 0 };
                js.j[ji++] = { xh + (size_t)toff[t]*HID, xl + (size_t)toff[t]*HID,
                               wveh + (size_t)mm*16384, wvel + (size_t)mm*16384,
                               bve + mm*128, nullptr, nullptr,
                               veb[e], ns[t], 0 };
            }
        }
        gemm_ws<<<dim3(gx, 13), 256, 0, stream>>>(js);

        // attention
        hipMemsetAsync(oacc, 0, (size_t)NTOT*HID*4, stream);
        for (int e = 0; e < 5; e++) {
            int dt = DT[e];
            attn_edge<<<(ns[dt]+3)/4, 256, 0, stream>>>(qb + (size_t)toff[dt]*HID, keb[e], veb[e],
                off[e], csrc[e], p_rel + (size_t)(l*5 + e)*NH,
                oacc + (size_t)toff[dt]*HID, ns[dt]);
        }

        // epilogue: gelu pre-split + blended GEMM
        presplit<<<(n4+255)/256, 256, 0, stream>>>(oacc, xh, xl, n4, 1);
        Jobs je = {};
        for (int t = 0; t < 3; t++) {
            int m = l*3 + t;
            je.j[t] = { xh + (size_t)toff[t]*HID, xl + (size_t)toff[t]*HID,
                        wah + (size_t)m*16384, wal + (size_t)m*16384,
                        ba + (size_t)m*HID,
                        cur + (size_t)toff[t]*HID, skipp + m,
                        ((l == 0) ? xsB : outp) + (size_t)toff[t]*HID, ns[t], 1 };
        }
        gemm_ws<<<dim3(gx, 3), 256, 0, stream>>>(je);
    }
}

// Round 5
// 738.085 us; speedup vs baseline: 2.0945x; 1.3780x over previous
//
#include <hip/hip_runtime.h>
#include <math.h>

#define HID 128

typedef __bf16 bf16x8 __attribute__((ext_vector_type(8)));
typedef float f32x4 __attribute__((ext_vector_type(4)));

__device__ __forceinline__ float gelu_f(float x) {
    float x3 = x*x*x;
    return 0.5f*x*(1.f + tanhf(0.7978845608028654f*(x + 0.044715f*x3)));
}
__device__ __forceinline__ unsigned short bf16_rn(float x) {
    unsigned int u = __float_as_uint(x);
    unsigned int r = (u + 0x7FFFu + ((u >> 16) & 1u)) >> 16;
    return (unsigned short)r;
}
__device__ __forceinline__ void split2(float x, unsigned short& h, unsigned short& l) {
    h = bf16_rn(x);
    float hf = __uint_as_float(((unsigned int)h) << 16);
    l = bf16_rn(x - hf);
}
__device__ __forceinline__ float blo(unsigned int u){ return __uint_as_float(u << 16); }
__device__ __forceinline__ float bhi(unsigned int u){ return __uint_as_float(u & 0xffff0000u); }

// ---- weight prep job table: W [K][128] f32 -> hi/lo bf16 [col][K] ----
struct WJobs { const float* in[15]; unsigned short* hi[15]; unsigned short* lo[15]; int kbits[15]; };
__global__ __launch_bounds__(256) void wprep(WJobs p) {
    int z = blockIdx.y;
    int kbits = p.kbits[z];
    int K = 1 << kbits;
    int idx = blockIdx.x * 256 + threadIdx.x;
    if (idx >= (K << 7)) return;
    int col = idx >> kbits, k = idx & (K - 1);
    float v = p.in[z][(size_t)k * 128 + col];
    unsigned short h, l; split2(v, h, l);
    p.hi[z][idx] = h; p.lo[z][idx] = l;
}

// ---- fused relation weights (ke: Wk*a_rel, ve: Wv*m_rel), z in [0,20) ----
__global__ __launch_bounds__(256) void fuse_w(const float* __restrict__ Wk, const float* __restrict__ Wv,
        const float* __restrict__ a_rel, const float* __restrict__ m_rel,
        unsigned short* __restrict__ keh, unsigned short* __restrict__ kel,
        unsigned short* __restrict__ veh, unsigned short* __restrict__ vel) {
    const int STm[5] = {2,0,0,1,1};
    int z = blockIdx.y;
    int m = (z < 10) ? z : z - 10;
    const float* W = (z < 10) ? Wk : Wv;
    const float* rel = (z < 10) ? a_rel : m_rel;
    unsigned short* oh = (z < 10) ? keh : veh;
    unsigned short* ol = (z < 10) ? kel : vel;
    int l = m / 5, e = m % 5, st = STm[e];
    int idx = blockIdx.x * 256 + threadIdx.x;
    int col = idx >> 7, c = idx & 127;
    int h = col >> 4, ep = col & 15;
    const float* w = W + (size_t)(l*3 + st) * 16384;
    const float* r = rel + (size_t)m * 2048 + h * 256;
    float s = 0.f;
    #pragma unroll
    for (int d = 0; d < 16; d++) s += w[c * 128 + h * 16 + d] * r[d * 16 + ep];
    unsigned short hh, ll; split2(s, hh, ll);
    oh[(size_t)m * 16384 + idx] = hh;
    ol[(size_t)m * 16384 + idx] = ll;
}

__global__ void fuse_b(const float* __restrict__ bk, const float* __restrict__ bv,
                       const float* __restrict__ a_rel, const float* __restrict__ m_rel,
                       float* __restrict__ obk, float* __restrict__ obv) {
    const int STm[5] = {2,0,0,1,1};
    int z = blockIdx.y;
    int m = (z < 10) ? z : z - 10;
    const float* b = (z < 10) ? bk : bv;
    const float* rel = (z < 10) ? a_rel : m_rel;
    float* ob = (z < 10) ? obk : obv;
    int l = m / 5, e = m % 5, st = STm[e];
    int col = threadIdx.x;
    int h = col >> 4, ep = col & 15;
    const float* bb = b + (l*3 + st) * 128;
    const float* r = rel + (size_t)m * 2048 + h * 256;
    float s = 0.f;
    #pragma unroll
    for (int d = 0; d < 16; d++) s += bb[h*16 + d] * r[d*16 + ep];
    ob[m * 128 + col] = s;
}

// ---- init projection GEMM: 64x128 tile, A f32 inline split, job table ----
struct IJob { const float* A; const unsigned short* Wh; const unsigned short* Wl;
              const float* bias; float* C; int N; int Kfull; int kbeg; int kend; };
struct IJobs { IJob j[4]; };

__global__ __launch_bounds__(256) void gemm_init(IJobs js) {
    IJob jb = js.j[blockIdx.y];
    int brow = blockIdx.x * 64;
    if (brow >= jb.N) return;
    __shared__ unsigned short Ah[2048], Al[2048], Bh[4096], Bl[4096];
    const int tid = threadIdx.x;
    const int wave = tid >> 6, lane = tid & 63;
    const int wr = wave >> 1, wc = wave & 1;
    const int lrow = lane & 15, lkg = lane >> 4;
    const int Kf = jb.Kfull, N = jb.N;

    f32x4 acc[2][4];
    #pragma unroll
    for (int i = 0; i < 2; i++)
        #pragma unroll
        for (int j = 0; j < 4; j++) acc[i][j] = (f32x4){0.f,0.f,0.f,0.f};

    for (int k0 = jb.kbeg; k0 < jb.kend; k0 += 32) {
        #pragma unroll
        for (int it = 0; it < 2; it++) {
            int c = tid + it*256;                 // 512 chunks of 4 floats
            int row = c >> 3, ks = (c & 7) * 4;
            int gr = brow + row; gr = (gr < N) ? gr : (N - 1);
            float4 v = *(const float4*)(jb.A + (size_t)gr * Kf + k0 + ks);
            ushort4 h, l;
            split2(v.x, h.x, l.x); split2(v.y, h.y, l.y);
            split2(v.z, h.z, l.z); split2(v.w, h.w, l.w);
            int o = ((ks >> 3) * 64 + row) * 8 + (ks & 7);
            *(ushort4*)&Ah[o] = h;
            *(ushort4*)&Al[o] = l;
        }
        #pragma unroll
        for (int it = 0; it < 2; it++) {
            int c = tid + it*256;                 // 512 chunks of 8 shorts
            int col = c >> 2, ks8 = (c & 3) * 8;
            size_t go = (size_t)col * Kf + k0 + ks8;
            int o = ((ks8 >> 3) * 128 + col) * 8;
            *(uint4*)&Bh[o] = *(const uint4*)(jb.Wh + go);
            *(uint4*)&Bl[o] = *(const uint4*)(jb.Wl + go);
        }
        __syncthreads();
        bf16x8 ah[2], al_[2], bh[4], bl_[4];
        #pragma unroll
        for (int i = 0; i < 2; i++) {
            int o = (lkg*64 + wr*32 + i*16 + lrow) * 8;
            ah[i] = *(const bf16x8*)&Ah[o];
            al_[i] = *(const bf16x8*)&Al[o];
        }
        #pragma unroll
        for (int j = 0; j < 4; j++) {
            int o = (lkg*128 + wc*64 + j*16 + lrow) * 8;
            bh[j] = *(const bf16x8*)&Bh[o];
            bl_[j] = *(const bf16x8*)&Bl[o];
        }
        #pragma unroll
        for (int i = 0; i < 2; i++)
            #pragma unroll
            for (int j = 0; j < 4; j++) {
                acc[i][j] = __builtin_amdgcn_mfma_f32_16x16x32_bf16(ah[i], bh[j], acc[i][j], 0,0,0);
                acc[i][j] = __builtin_amdgcn_mfma_f32_16x16x32_bf16(ah[i], bl_[j], acc[i][j], 0,0,0);
                acc[i][j] = __builtin_amdgcn_mfma_f32_16x16x32_bf16(al_[i], bh[j], acc[i][j], 0,0,0);
            }
        __syncthreads();
    }

    #pragma unroll
    for (int i = 0; i < 2; i++) {
        int rbase = brow + wr*32 + i*16 + (lane >> 4) * 4;
        #pragma unroll
        for (int j = 0; j < 4; j++) {
            int col = wc*64 + j*16 + lrow;
            float bv = jb.bias ? jb.bias[col] : 0.f;
            #pragma unroll
            for (int rr = 0; rr < 4; rr++) {
                int gr = rbase + rr;
                if (gr < N) jb.C[(size_t)gr * 128 + col] = acc[i][j][rr] + bv;
            }
        }
    }
}

// ---- main GEMM: 64x128 tile, K=128, A pre-split, job table, 3 output modes ----
struct Job { const unsigned short* Ah; const unsigned short* Al;
             const unsigned short* Wh; const unsigned short* Wl;
             const float* bias; const float* res; const float* skipv;
             void* C; int N; int mode; };
struct Jobs { Job j[13]; };

__global__ __launch_bounds__(256) void gemm_ws(Jobs js) {
    Job jb = js.j[blockIdx.y];
    int brow = blockIdx.x * 64;
    if (brow >= jb.N) return;
    __shared__ unsigned short Ah[2048], Al[2048], Bh[4096], Bl[4096];
    const int tid = threadIdx.x;
    const int wave = tid >> 6, lane = tid & 63;
    const int wr = wave >> 1, wc = wave & 1;
    const int lrow = lane & 15, lkg = lane >> 4;
    const int N = jb.N;

    f32x4 acc[2][4];
    #pragma unroll
    for (int i = 0; i < 2; i++)
        #pragma unroll
        for (int j = 0; j < 4; j++) acc[i][j] = (f32x4){0.f,0.f,0.f,0.f};

    #pragma unroll
    for (int k0 = 0; k0 < 128; k0 += 32) {
        {
            int c = tid;                          // 256 chunks of 8 shorts (A: 64x32)
            int row = c >> 2, ks8 = (c & 3) * 8;
            int gr = brow + row; gr = (gr < N) ? gr : (N - 1);
            size_t ga = (size_t)gr * 128 + k0 + ks8;
            int o = ((ks8 >> 3) * 64 + row) * 8;
            *(uint4*)&Ah[o] = *(const uint4*)(jb.Ah + ga);
            *(uint4*)&Al[o] = *(const uint4*)(jb.Al + ga);
        }
        #pragma unroll
        for (int it = 0; it < 2; it++) {
            int c = tid + it*256;                 // 512 chunks (B: 128x32)
            int col = c >> 2, ks8 = (c & 3) * 8;
            size_t go = (size_t)col * 128 + k0 + ks8;
            int o = ((ks8 >> 3) * 128 + col) * 8;
            *(uint4*)&Bh[o] = *(const uint4*)(jb.Wh + go);
            *(uint4*)&Bl[o] = *(const uint4*)(jb.Wl + go);
        }
        __syncthreads();
        bf16x8 ah[2], al_[2], bh[4], bl_[4];
        #pragma unroll
        for (int i = 0; i < 2; i++) {
            int o = (lkg*64 + wr*32 + i*16 + lrow) * 8;
            ah[i] = *(const bf16x8*)&Ah[o];
            al_[i] = *(const bf16x8*)&Al[o];
        }
        #pragma unroll
        for (int j = 0; j < 4; j++) {
            int o = (lkg*128 + wc*64 + j*16 + lrow) * 8;
            bh[j] = *(const bf16x8*)&Bh[o];
            bl_[j] = *(const bf16x8*)&Bl[o];
        }
        #pragma unroll
        for (int i = 0; i < 2; i++)
            #pragma unroll
            for (int j = 0; j < 4; j++) {
                acc[i][j] = __builtin_amdgcn_mfma_f32_16x16x32_bf16(ah[i], bh[j], acc[i][j], 0,0,0);
                acc[i][j] = __builtin_amdgcn_mfma_f32_16x16x32_bf16(ah[i], bl_[j], acc[i][j], 0,0,0);
                acc[i][j] = __builtin_amdgcn_mfma_f32_16x16x32_bf16(al_[i], bh[j], acc[i][j], 0,0,0);
            }
        __syncthreads();
    }

    float beta = 0.f;
    if (jb.mode == 1) beta = 1.f / (1.f + __expf(-jb.skipv[0]));
    #pragma unroll
    for (int i = 0; i < 2; i++) {
        int rbase = brow + wr*32 + i*16 + (lane >> 4) * 4;
        #pragma unroll
        for (int j = 0; j < 4; j++) {
            int col = wc*64 + j*16 + lrow;
            float bv = jb.bias[col];
            #pragma unroll
            for (int rr = 0; rr < 4; rr++) {
                int gr = rbase + rr;
                if (gr < N) {
                    float cv = acc[i][j][rr] + bv;
                    if (jb.mode == 2) {
                        ((unsigned short*)jb.C)[(size_t)gr * 128 + col] = bf16_rn(cv);
                    } else {
                        if (jb.mode == 1) {
                            float r = jb.res[(size_t)gr * 128 + col];
                            cv = beta * cv + (1.f - beta) * r;
                        }
                        ((float*)jb.C)[(size_t)gr * 128 + col] = cv;
                    }
                }
            }
        }
    }
}

// ---- fused attention over all 5 edge types; bf16 gathers; plain stores ----
struct AttnP {
    const unsigned int* q[5];
    const unsigned int* ke[5];
    const unsigned int* ve[5];
    const int* off[5];
    const int* csr[5];
    float* out[5];
    const float* prel;
    int base[6];
    int ndst[5];
};

__global__ __launch_bounds__(256) void attn_fused(AttnP p) {
    int b = blockIdx.x;
    int z = 0;
    #pragma unroll
    for (int k = 1; k < 5; k++) if (b >= p.base[k]) z = k;
    int node = (b - p.base[z]) * 4 + (threadIdx.x >> 6);
    if (node >= p.ndst[z]) return;
    int lane = threadIdx.x & 63;
    int h = lane >> 3;
    int e0 = p.off[z][node], e1 = p.off[z][node + 1];
    if (e0 == e1) return;
    unsigned int qu = p.q[z][(size_t)node * 64 + lane];
    float qx = blo(qu), qy = bhi(qu);
    float pr = p.prel[z * 8 + h] * 0.25f;
    const unsigned int* KE = p.ke[z];
    const unsigned int* VE = p.ve[z];
    const int* srcs = p.csr[z];
    float m = -INFINITY, s = 0.f, ax = 0.f, ay = 0.f;
    int i = e0;
    int sn = srcs[i];
    unsigned int kn = KE[(size_t)sn * 64 + lane];
    unsigned int vn = VE[(size_t)sn * 64 + lane];
    while (true) {
        unsigned int ku = kn, vu = vn;
        ++i;
        if (i < e1) {
            int s2 = srcs[i];
            kn = KE[(size_t)s2 * 64 + lane];
            vn = VE[(size_t)s2 * 64 + lane];
        }
        float part = qx * blo(ku) + qy * bhi(ku);
        part += __shfl_xor(part, 1);
        part += __shfl_xor(part, 2);
        part += __shfl_xor(part, 4);
        float alpha = part * pr;
        float mn = fmaxf(m, alpha);
        float cc = __expf(m - mn);
        float pe = __expf(alpha - mn);
        s = s * cc + pe;
        ax = ax * cc + pe * blo(vu);
        ay = ay * cc + pe * bhi(vu);
        m = mn;
        if (i >= e1) break;
    }
    float inv = 1.f / (s + 1e-16f);
    float* o = p.out[z] + (size_t)node * 128 + lane * 2;
    o[0] = ax * inv;
    o[1] = ay * inv;
}

// ---- presplit kernels ----
__global__ __launch_bounds__(256) void presplit_init(const float* __restrict__ pA, const float* __restrict__ pB,
        float* __restrict__ xsA, unsigned short* __restrict__ xh, unsigned short* __restrict__ xl,
        float* __restrict__ oA, float* __restrict__ oB, int n4, int p0, int p1) {
    int i = blockIdx.x * 256 + threadIdx.x;
    if (i >= n4) return;
    float4 v;
    if (i >= p0 && i < p1) {
        float4 a = ((const float4*)pA)[i - p0];
        float4 b = ((const float4*)pB)[i - p0];
        v = make_float4(a.x+b.x, a.y+b.y, a.z+b.z, a.w+b.w);
        ((float4*)xsA)[i] = v;
    } else v = ((const float4*)xsA)[i];
    ushort4 h, l;
    split2(v.x, h.x, l.x); split2(v.y, h.y, l.y);
    split2(v.z, h.z, l.z); split2(v.w, h.w, l.w);
    ((ushort4*)xh)[i] = h; ((ushort4*)xl)[i] = l;
    float4 z4 = make_float4(0.f,0.f,0.f,0.f);
    ((float4*)oA)[i] = z4; ((float4*)oB)[i] = z4;
}

__global__ __launch_bounds__(256) void presplit_plain(const float* __restrict__ x,
        unsigned short* __restrict__ xh, unsigned short* __restrict__ xl,
        float* __restrict__ oA, float* __restrict__ oB, int n4) {
    int i = blockIdx.x * 256 + threadIdx.x;
    if (i >= n4) return;
    float4 v = ((const float4*)x)[i];
    ushort4 h, l;
    split2(v.x, h.x, l.x); split2(v.y, h.y, l.y);
    split2(v.z, h.z, l.z); split2(v.w, h.w, l.w);
    ((ushort4*)xh)[i] = h; ((ushort4*)xl)[i] = l;
    float4 z4 = make_float4(0.f,0.f,0.f,0.f);
    ((float4*)oA)[i] = z4; ((float4*)oB)[i] = z4;
}

__global__ __launch_bounds__(256) void presplit_gelu(const float* __restrict__ oA, const float* __restrict__ oB,
        unsigned short* __restrict__ xh, unsigned short* __restrict__ xl, int n4) {
    int i = blockIdx.x * 256 + threadIdx.x;
    if (i >= n4) return;
    float4 a = ((const float4*)oA)[i];
    float4 b = ((const float4*)oB)[i];
    float4 v = make_float4(gelu_f(a.x+b.x), gelu_f(a.y+b.y), gelu_f(a.z+b.z), gelu_f(a.w+b.w));
    ushort4 h, l;
    split2(v.x, h.x, l.x); split2(v.y, h.y, l.y);
    split2(v.z, h.z, l.z); split2(v.w, h.w, l.w);
    ((ushort4*)xh)[i] = h; ((ushort4*)xl)[i] = l;
}

// ---- CSR build ----
struct CsrP {
    const int* esrc[5]; const int* edst[5];
    int* cnt[5]; int* off[5]; int* off2[5]; int* csr[5]; int* bsum[5];
    int E[5]; int N[5]; int nb[5];
};

__global__ __launch_bounds__(256) void csr_hist(CsrP p) {
    int z = blockIdx.z;
    int i = blockIdx.x * 256 + threadIdx.x;
    if (i < p.E[z]) atomicAdd(&p.cnt[z][p.edst[z][i]], 1);
}

__global__ __launch_bounds__(256) void csr_p1(CsrP p) {
    int z = blockIdx.z, b = blockIdx.x;
    int N = p.N[z];
    if (b * 1024 >= N) return;
    const int* cnt = p.cnt[z];
    __shared__ int wtot[4];
    int tid = threadIdx.x, lane = tid & 63, w = tid >> 6;
    int base = b * 1024 + tid * 4;
    int s = 0;
    #pragma unroll
    for (int k = 0; k < 4; k++) { int i = base + k; if (i < N) s += cnt[i]; }
    int incl = s;
    #pragma unroll
    for (int o = 1; o < 64; o <<= 1) { int t = __shfl_up(incl, o); if (lane >= o) incl += t; }
    if (lane == 63) wtot[w] = incl;
    __syncthreads();
    if (tid == 0) p.bsum[z][b] = wtot[0] + wtot[1] + wtot[2] + wtot[3];
}

__global__ void csr_p2(CsrP p) {
    int z = blockIdx.z;
    if (threadIdx.x == 0) {
        int nb = p.nb[z]; int run = 0; int* bs = p.bsum[z];
        for (int b = 0; b < nb; b++) { int t = bs[b]; bs[b] = run; run += t; }
        p.off[z][p.N[z]] = run;
        p.off2[z][p.N[z]] = run;
    }
}

__global__ __launch_bounds__(256) void csr_p3(CsrP p) {
    int z = blockIdx.z, b = blockIdx.x;
    int N = p.N[z];
    if (b * 1024 >= N) return;
    const int* cnt = p.cnt[z]; int* off = p.off[z]; int* off2 = p.off2[z];
    __shared__ int wtot[4];
    int tid = threadIdx.x, lane = tid & 63, w = tid >> 6;
    int base = b * 1024 + tid * 4;
    int v0=0,v1=0,v2=0,v3=0;
    if (base+0 < N) v0 = cnt[base+0];
    if (base+1 < N) v1 = cnt[base+1];
    if (base+2 < N) v2 = cnt[base+2];
    if (base+3 < N) v3 = cnt[base+3];
    int tsum = v0+v1+v2+v3;
    int incl = tsum;
    #pragma unroll
    for (int o = 1; o < 64; o <<= 1) { int t = __shfl_up(incl, o); if (lane >= o) incl += t; }
    if (lane == 63) wtot[w] = incl;
    __syncthreads();
    int we = 0;
    for (int k = 0; k < w; k++) we += wtot[k];
    int texcl = we + incl - tsum + p.bsum[z][b];
    int o0 = texcl, o1 = texcl+v0, o2 = texcl+v0+v1, o3 = texcl+v0+v1+v2;
    if (base+0 < N) { off[base+0]=o0; off2[base+0]=o0; }
    if (base+1 < N) { off[base+1]=o1; off2[base+1]=o1; }
    if (base+2 < N) { off[base+2]=o2; off2[base+2]=o2; }
    if (base+3 < N) { off[base+3]=o3; off2[base+3]=o3; }
}

__global__ __launch_bounds__(256) void csr_scatter(CsrP p) {
    int z = blockIdx.z;
    int i = blockIdx.x * 256 + threadIdx.x;
    if (i < p.E[z]) {
        int d = p.edst[z][i];
        int pos = atomicAdd(&p.off2[z][d], 1);
        p.csr[z][pos] = p.esrc[z][i];
    }
}

extern "C" void kernel_launch(void* const* d_in, const int* in_sizes, int n_in,
                              void* d_out, int out_size, void* d_ws, size_t ws_size,
                              hipStream_t stream)
{
    const float* xin[3] = {(const float*)d_in[0], (const float*)d_in[1], (const float*)d_in[2]};
    const int FIN[3] = {512, 1024, 128};
    const int KBITS[3] = {9, 10, 7};
    int ns[3];
    for (int t = 0; t < 3; t++) ns[t] = in_sizes[t] / FIN[t];
    const int* esrc[5]; const int* edst[5]; int E[5];
    for (int e = 0; e < 5; e++) { esrc[e] = (const int*)d_in[3+2*e]; edst[e] = (const int*)d_in[4+2*e]; E[e] = in_sizes[3+2*e]; }
    const float* Win[3] = {(const float*)d_in[13], (const float*)d_in[15], (const float*)d_in[17]};
    const float* bin[3] = {(const float*)d_in[14], (const float*)d_in[16], (const float*)d_in[18]};
    const float* Wk = (const float*)d_in[19]; const float* Wq = (const float*)d_in[20];
    const float* Wv = (const float*)d_in[21]; const float* Wa = (const float*)d_in[22];
    const float* bk = (const float*)d_in[23]; const float* bq = (const float*)d_in[24];
    const float* bv = (const float*)d_in[25]; const float* ba = (const float*)d_in[26];
    const float* skipp = (const float*)d_in[27];
    const float* a_rel = (const float*)d_in[28];
    const float* m_rel = (const float*)d_in[29];
    const float* p_rel = (const float*)d_in[30];

    static const int ST[5] = {2,0,0,1,1}, DT[5] = {0,2,1,0,1};

    int NTOT = ns[0] + ns[1] + ns[2];
    int toff[3] = {0, ns[0], ns[0] + ns[1]};
    int maxN = ns[0]; for (int t = 1; t < 3; t++) if (ns[t] > maxN) maxN = ns[t];
    int maxE = E[0]; for (int e = 1; e < 5; e++) if (E[e] > maxE) maxE = E[e];

    // ---- workspace carve ----
    float* fp = (float*)d_ws;
    float* xsA = fp; fp += (size_t)NTOT*HID;
    float* xsB = fp; fp += (size_t)NTOT*HID;
    float* oaccA = fp; fp += (size_t)NTOT*HID;
    float* oaccB = fp; fp += (size_t)NTOT*HID;
    float* pA = fp; fp += (size_t)ns[1]*HID;
    float* pB = fp; fp += (size_t)ns[1]*HID;
    float* bke = fp; fp += 10*128;
    float* bve = fp; fp += 10*128;
    unsigned short* up = (unsigned short*)fp;
    unsigned short* xh = up; up += (size_t)NTOT*HID;
    unsigned short* xl = up; up += (size_t)NTOT*HID;
    unsigned short* qbf = up; up += (size_t)NTOT*HID;
    unsigned short* kebf[5]; unsigned short* vebf[5];
    for (int e = 0; e < 5; e++) {
        kebf[e] = up; up += (size_t)ns[ST[e]]*HID;
        vebf[e] = up; up += (size_t)ns[ST[e]]*HID;
    }
    unsigned short* wih[3]; unsigned short* wil[3];
    for (int t = 0; t < 3; t++) { wih[t] = up; up += (size_t)FIN[t]*HID; wil[t] = up; up += (size_t)FIN[t]*HID; }
    unsigned short* wqh = up; up += 6*16384; unsigned short* wql = up; up += 6*16384;
    unsigned short* wah = up; up += 6*16384; unsigned short* wal = up; up += 6*16384;
    unsigned short* wkeh = up; up += 10*16384; unsigned short* wkel = up; up += 10*16384;
    unsigned short* wveh = up; up += 10*16384; unsigned short* wvel = up; up += 10*16384;
    uintptr_t ip_ = ((uintptr_t)up + 255) & ~(uintptr_t)255;
    int* ip = (int*)ip_;
    int* off[5]; int* off2[5]; int* csrc[5]; int* cntp[5]; int* bsump[5];
    for (int e = 0; e < 5; e++) { off[e] = ip; ip += ns[DT[e]] + 1; }
    for (int e = 0; e < 5; e++) { off2[e] = ip; ip += ns[DT[e]] + 1; }
    for (int e = 0; e < 5; e++) { csrc[e] = ip; ip += E[e]; }
    int* cntbase = ip; int cnt_tot = 0;
    for (int e = 0; e < 5; e++) { cntp[e] = cntbase + cnt_tot; cnt_tot += ns[DT[e]]; }
    ip += cnt_tot;
    for (int e = 0; e < 5; e++) { bsump[e] = ip; ip += 64; }

    // ---- weight prep (one dispatch) ----
    WJobs wj;
    for (int t = 0; t < 3; t++) { wj.in[t]=Win[t]; wj.hi[t]=wih[t]; wj.lo[t]=wil[t]; wj.kbits[t]=KBITS[t]; }
    for (int j = 0; j < 6; j++) {
        wj.in[3+j]=Wq + (size_t)j*16384; wj.hi[3+j]=wqh + (size_t)j*16384; wj.lo[3+j]=wql + (size_t)j*16384; wj.kbits[3+j]=7;
        wj.in[9+j]=Wa + (size_t)j*16384; wj.hi[9+j]=wah + (size_t)j*16384; wj.lo[9+j]=wal + (size_t)j*16384; wj.kbits[9+j]=7;
    }
    wprep<<<dim3(512, 15), 256, 0, stream>>>(wj);
    fuse_w<<<dim3(64, 20), 256, 0, stream>>>(Wk, Wv, a_rel, m_rel, wkeh, wkel, wveh, wvel);
    fuse_b<<<dim3(1, 20), 128, 0, stream>>>(bk, bv, a_rel, m_rel, bke, bve);

    // ---- CSR build ----
    CsrP cp;
    for (int e = 0; e < 5; e++) {
        cp.esrc[e]=esrc[e]; cp.edst[e]=edst[e];
        cp.cnt[e]=cntp[e]; cp.off[e]=off[e]; cp.off2[e]=off2[e]; cp.csr[e]=csrc[e]; cp.bsum[e]=bsump[e];
        cp.E[e]=E[e]; cp.N[e]=ns[DT[e]]; cp.nb[e]=(ns[DT[e]] + 1023)/1024;
    }
    int nbmax = (maxN + 1023) / 1024;
    hipMemsetAsync(cntbase, 0, (size_t)cnt_tot * 4, stream);
    csr_hist<<<dim3((maxE+255)/256, 1, 5), 256, 0, stream>>>(cp);
    csr_p1<<<dim3(nbmax, 1, 5), 256, 0, stream>>>(cp);
    csr_p2<<<dim3(1, 1, 5), 64, 0, stream>>>(cp);
    csr_p3<<<dim3(nbmax, 1, 5), 256, 0, stream>>>(cp);
    csr_scatter<<<dim3((maxE+255)/256, 1, 5), 256, 0, stream>>>(cp);

    // ---- initial projections (one dispatch; protein split-K=2) ----
    IJobs ij;
    ij.j[0] = { xin[0], wih[0], wil[0], bin[0], xsA,                         ns[0], 512, 0, 512 };
    ij.j[1] = { xin[2], wih[2], wil[2], bin[2], xsA + (size_t)toff[2]*HID,   ns[2], 128, 0, 128 };
    ij.j[2] = { xin[1], wih[1], wil[1], bin[1], pA,                          ns[1], 1024, 0, 512 };
    ij.j[3] = { xin[1], wih[1], wil[1], nullptr, pB,                         ns[1], 1024, 512, 1024 };
    int gx = (maxN + 63) / 64;
    gemm_init<<<dim3(gx, 4), 256, 0, stream>>>(ij);

    int n4 = NTOT * HID / 4;
    int p0 = toff[1] * (HID/4), p1 = toff[2] * (HID/4);
    int psg = (n4 + 255) / 256;
    presplit_init<<<psg, 256, 0, stream>>>(pA, pB, xsA, xh, xl, oaccA, oaccB, n4, p0, p1);

    float* outp = (float*)d_out;

    // attention grid setup
    int abase[6]; abase[0] = 0;
    for (int e = 0; e < 5; e++) abase[e+1] = abase[e] + (ns[DT[e]] + 3) / 4;
    float* outsel[5] = { oaccA, oaccA + (size_t)toff[2]*HID, oaccA + (size_t)toff[1]*HID,
                         oaccB, oaccB + (size_t)toff[1]*HID };

    for (int l = 0; l < 2; l++) {
        float* cur = (l == 0) ? xsA : xsB;
        if (l == 1) presplit_plain<<<psg, 256, 0, stream>>>(xsB, xh, xl, oaccA, oaccB, n4);

        // main GEMM: q + ke/ve for all relations (one dispatch, 13 jobs)
        Jobs js = {};
        int ji = 0;
        for (int t = 0; t < 3; t++) {
            int m = l*3 + t;
            js.j[ji++] = { xh + (size_t)toff[t]*HID, xl + (size_t)toff[t]*HID,
                           wqh + (size_t)m*16384, wql + (size_t)m*16384,
                           bq + (size_t)m*HID, nullptr, nullptr,
                           qbf + (size_t)toff[t]*HID, ns[t], 2 };
            for (int e = 0; e < 5; e++) {
                if (ST[e] != t) continue;
                int mm = l*5 + e;
                js.j[ji++] = { xh + (size_t)toff[t]*HID, xl + (size_t)toff[t]*HID,
                               wkeh + (size_t)mm*16384, wkel + (size_t)mm*16384,
                               bke + mm*128, nullptr, nullptr,
                               kebf[e], ns[t], 2 };
                js.j[ji++] = { xh + (size_t)toff[t]*HID, xl + (size_t)toff[t]*HID,
                               wveh + (size_t)mm*16384, wvel + (size_t)mm*16384,
                               bve + mm*128, nullptr, nullptr,
                               vebf[e], ns[t], 2 };
            }
        }
        gemm_ws<<<dim3(gx, 13), 256, 0, stream>>>(js);

        // fused attention (one dispatch)
        AttnP ap;
        for (int e = 0; e < 5; e++) {
            ap.q[e] = (const unsigned int*)(qbf + (size_t)toff[DT[e]]*HID);
            ap.ke[e] = (const unsigned int*)kebf[e];
            ap.ve[e] = (const unsigned int*)vebf[e];
            ap.off[e] = off[e]; ap.csr[e] = csrc[e];
            ap.out[e] = outsel[e];
            ap.ndst[e] = ns[DT[e]];
        }
        for (int k = 0; k < 6; k++) ap.base[k] = abase[k];
        ap.prel = p_rel + l*40;
        attn_fused<<<abase[5], 256, 0, stream>>>(ap);

        // epilogue
        presplit_gelu<<<psg, 256, 0, stream>>>(oaccA, oaccB, xh, xl, n4);
        Jobs je = {};
        for (int t = 0; t < 3; t++) {
            int m = l*3 + t;
            je.j[t] = { xh + (size_t)toff[t]*HID, xl + (size_t)toff[t]*HID,
                        wah + (size_t)m*16384, wal + (size_t)m*16384,
                        ba + (size_t)m*HID,
                        cur + (size_t)toff[t]*HID, skipp + m,
                        ((l == 0) ? xsB : outp) + (size_t)toff[t]*HID, ns[t], 1 };
        }
        gemm_ws<<<dim3(gx, 3), 256, 0, stream>>>(je);
    }
}

// Round 7
// 699.355 us; speedup vs baseline: 2.2105x; 1.0554x over previous
//
#include <hip/hip_runtime.h>
#include <math.h>

#define HID 128

typedef __bf16 bf16x8 __attribute__((ext_vector_type(8)));
typedef float f32x4 __attribute__((ext_vector_type(4)));

__device__ __forceinline__ float gelu_f(float x) {
    float z = 0.7978845608028654f * (x + 0.044715f * x * x * x);
    float az = fabsf(z);
    float e = __expf(-2.f * az);
    float t = (1.f - e) / (1.f + e);
    t = (z < 0.f) ? -t : t;
    return 0.5f * x * (1.f + t);
}
__device__ __forceinline__ unsigned short bf16_rn(float x) {
    unsigned int u = __float_as_uint(x);
    unsigned int r = (u + 0x7FFFu + ((u >> 16) & 1u)) >> 16;
    return (unsigned short)r;
}
__device__ __forceinline__ void split2(float x, unsigned short& h, unsigned short& l) {
    h = bf16_rn(x);
    float hf = __uint_as_float(((unsigned int)h) << 16);
    l = bf16_rn(x - hf);
}
__device__ __forceinline__ float blo(unsigned int u){ return __uint_as_float(u << 16); }
__device__ __forceinline__ float bhi(unsigned int u){ return __uint_as_float(u & 0xffff0000u); }

// ---- weight prep job table: W [K][128] f32 -> hi/lo bf16 [col][K] ----
struct WJobs { const float* in[15]; unsigned short* hi[15]; unsigned short* lo[15]; int kbits[15]; };
__global__ __launch_bounds__(256) void wprep(WJobs p) {
    int z = blockIdx.y;
    int kbits = p.kbits[z];
    int K = 1 << kbits;
    int idx = blockIdx.x * 256 + threadIdx.x;
    if (idx >= (K << 7)) return;
    int col = idx >> kbits, k = idx & (K - 1);
    float v = p.in[z][(size_t)k * 128 + col];
    unsigned short h, l; split2(v, h, l);
    p.hi[z][idx] = h; p.lo[z][idx] = l;
}

// ---- fused relation weights (ke: Wk*a_rel, ve: Wv*m_rel), z in [0,20) ----
__global__ __launch_bounds__(256) void fuse_w(const float* __restrict__ Wk, const float* __restrict__ Wv,
        const float* __restrict__ a_rel, const float* __restrict__ m_rel,
        unsigned short* __restrict__ keh, unsigned short* __restrict__ kel,
        unsigned short* __restrict__ veh, unsigned short* __restrict__ vel) {
    const int STm[5] = {2,0,0,1,1};
    int z = blockIdx.y;
    int m = (z < 10) ? z : z - 10;
    const float* W = (z < 10) ? Wk : Wv;
    const float* rel = (z < 10) ? a_rel : m_rel;
    unsigned short* oh = (z < 10) ? keh : veh;
    unsigned short* ol = (z < 10) ? kel : vel;
    int l = m / 5, e = m % 5, st = STm[e];
    int idx = blockIdx.x * 256 + threadIdx.x;
    int col = idx >> 7, c = idx & 127;
    int h = col >> 4, ep = col & 15;
    const float* w = W + (size_t)(l*3 + st) * 16384;
    const float* r = rel + (size_t)m * 2048 + h * 256;
    float s = 0.f;
    #pragma unroll
    for (int d = 0; d < 16; d++) s += w[c * 128 + h * 16 + d] * r[d * 16 + ep];
    unsigned short hh, ll; split2(s, hh, ll);
    oh[(size_t)m * 16384 + idx] = hh;
    ol[(size_t)m * 16384 + idx] = ll;
}

__global__ void fuse_b(const float* __restrict__ bk, const float* __restrict__ bv,
                       const float* __restrict__ a_rel, const float* __restrict__ m_rel,
                       float* __restrict__ obk, float* __restrict__ obv) {
    const int STm[5] = {2,0,0,1,1};
    int z = blockIdx.y;
    int m = (z < 10) ? z : z - 10;
    const float* b = (z < 10) ? bk : bv;
    const float* rel = (z < 10) ? a_rel : m_rel;
    float* ob = (z < 10) ? obk : obv;
    int l = m / 5, e = m % 5, st = STm[e];
    int col = threadIdx.x;
    int h = col >> 4, ep = col & 15;
    const float* bb = b + (l*3 + st) * 128;
    const float* r = rel + (size_t)m * 2048 + h * 256;
    float s = 0.f;
    #pragma unroll
    for (int d = 0; d < 16; d++) s += bb[h*16 + d] * r[d*16 + ep];
    ob[m * 128 + col] = s;
}

// ---- init projection GEMM: 64x128 tile, A f32 inline split, job table ----
struct IJob { const float* A; const unsigned short* Wh; const unsigned short* Wl;
              const float* bias; float* C; unsigned short* Ch; unsigned short* Cl;
              int N; int Kfull; int kbeg; int kend; };
struct IJobs { IJob j[4]; };

__global__ __launch_bounds__(256) void gemm_init(IJobs js) {
    IJob jb = js.j[blockIdx.y];
    int brow = blockIdx.x * 64;
    if (brow >= jb.N) return;
    __shared__ unsigned short Ah[2048], Al[2048], Bh[4096], Bl[4096];
    const int tid = threadIdx.x;
    const int wave = tid >> 6, lane = tid & 63;
    const int wr = wave >> 1, wc = wave & 1;
    const int lrow = lane & 15, lkg = lane >> 4;
    const int Kf = jb.Kfull, N = jb.N;

    f32x4 acc[2][4];
    #pragma unroll
    for (int i = 0; i < 2; i++)
        #pragma unroll
        for (int j = 0; j < 4; j++) acc[i][j] = (f32x4){0.f,0.f,0.f,0.f};

    for (int k0 = jb.kbeg; k0 < jb.kend; k0 += 32) {
        #pragma unroll
        for (int it = 0; it < 2; it++) {
            int c = tid + it*256;
            int row = c >> 3, ks = (c & 7) * 4;
            int gr = brow + row; gr = (gr < N) ? gr : (N - 1);
            float4 v = *(const float4*)(jb.A + (size_t)gr * Kf + k0 + ks);
            ushort4 h, l;
            split2(v.x, h.x, l.x); split2(v.y, h.y, l.y);
            split2(v.z, h.z, l.z); split2(v.w, h.w, l.w);
            int o = ((ks >> 3) * 64 + row) * 8 + (ks & 7);
            *(ushort4*)&Ah[o] = h;
            *(ushort4*)&Al[o] = l;
        }
        #pragma unroll
        for (int it = 0; it < 2; it++) {
            int c = tid + it*256;
            int col = c >> 2, ks8 = (c & 3) * 8;
            size_t go = (size_t)col * Kf + k0 + ks8;
            int o = ((ks8 >> 3) * 128 + col) * 8;
            *(uint4*)&Bh[o] = *(const uint4*)(jb.Wh + go);
            *(uint4*)&Bl[o] = *(const uint4*)(jb.Wl + go);
        }
        __syncthreads();
        bf16x8 ah[2], al_[2], bh[4], bl_[4];
        #pragma unroll
        for (int i = 0; i < 2; i++) {
            int o = (lkg*64 + wr*32 + i*16 + lrow) * 8;
            ah[i] = *(const bf16x8*)&Ah[o];
            al_[i] = *(const bf16x8*)&Al[o];
        }
        #pragma unroll
        for (int j = 0; j < 4; j++) {
            int o = (lkg*128 + wc*64 + j*16 + lrow) * 8;
            bh[j] = *(const bf16x8*)&Bh[o];
            bl_[j] = *(const bf16x8*)&Bl[o];
        }
        #pragma unroll
        for (int i = 0; i < 2; i++)
            #pragma unroll
            for (int j = 0; j < 4; j++) {
                acc[i][j] = __builtin_amdgcn_mfma_f32_16x16x32_bf16(ah[i], bh[j], acc[i][j], 0,0,0);
                acc[i][j] = __builtin_amdgcn_mfma_f32_16x16x32_bf16(ah[i], bl_[j], acc[i][j], 0,0,0);
                acc[i][j] = __builtin_amdgcn_mfma_f32_16x16x32_bf16(al_[i], bh[j], acc[i][j], 0,0,0);
            }
        __syncthreads();
    }

    #pragma unroll
    for (int i = 0; i < 2; i++) {
        int rbase = brow + wr*32 + i*16 + (lane >> 4) * 4;
        #pragma unroll
        for (int j = 0; j < 4; j++) {
            int col = wc*64 + j*16 + lrow;
            float bv = jb.bias ? jb.bias[col] : 0.f;
            #pragma unroll
            for (int rr = 0; rr < 4; rr++) {
                int gr = rbase + rr;
                if (gr < N) {
                    size_t idx = (size_t)gr * 128 + col;
                    float cv = acc[i][j][rr] + bv;
                    jb.C[idx] = cv;
                    if (jb.Ch) {
                        unsigned short h, l; split2(cv, h, l);
                        jb.Ch[idx] = h; jb.Cl[idx] = l;
                    }
                }
            }
        }
    }
}

// ---- main GEMM: 64x128 tile, K=128, job table ----
// A source: pre-split (Ah/Al) OR f32 gelu(A1[+A2]) inline split.
// mode 0: f32 out. mode 1: skip-blend f32 out (+optional split out). mode 2: bf16 out.
struct Job { const unsigned short* Ah; const unsigned short* Al;
             const float* A1; const float* A2;
             const unsigned short* Wh; const unsigned short* Wl;
             const float* bias; const float* res; const float* skipv;
             void* C; unsigned short* Ch; unsigned short* Cl;
             int N; int mode; };
struct Jobs { Job j[13]; };

__global__ __launch_bounds__(256) void gemm_ws(Jobs js) {
    Job jb = js.j[blockIdx.y];
    int brow = blockIdx.x * 64;
    if (brow >= jb.N) return;
    __shared__ unsigned short Ah[2048], Al[2048], Bh[4096], Bl[4096];
    const int tid = threadIdx.x;
    const int wave = tid >> 6, lane = tid & 63;
    const int wr = wave >> 1, wc = wave & 1;
    const int lrow = lane & 15, lkg = lane >> 4;
    const int N = jb.N;

    f32x4 acc[2][4];
    #pragma unroll
    for (int i = 0; i < 2; i++)
        #pragma unroll
        for (int j = 0; j < 4; j++) acc[i][j] = (f32x4){0.f,0.f,0.f,0.f};

    #pragma unroll
    for (int k0 = 0; k0 < 128; k0 += 32) {
        if (jb.A1) {
            #pragma unroll
            for (int it = 0; it < 2; it++) {
                int c = tid + it*256;
                int row = c >> 3, ks = (c & 7) * 4;
                int gr = brow + row; gr = (gr < N) ? gr : (N - 1);
                size_t ga = (size_t)gr * 128 + k0 + ks;
                float4 a = *(const float4*)(jb.A1 + ga);
                if (jb.A2) {
                    float4 b2 = *(const float4*)(jb.A2 + ga);
                    a.x += b2.x; a.y += b2.y; a.z += b2.z; a.w += b2.w;
                }
                a.x = gelu_f(a.x); a.y = gelu_f(a.y); a.z = gelu_f(a.z); a.w = gelu_f(a.w);
                ushort4 h, l;
                split2(a.x, h.x, l.x); split2(a.y, h.y, l.y);
                split2(a.z, h.z, l.z); split2(a.w, h.w, l.w);
                int o = ((ks >> 3) * 64 + row) * 8 + (ks & 7);
                *(ushort4*)&Ah[o] = h;
                *(ushort4*)&Al[o] = l;
            }
        } else {
            int c = tid;
            int row = c >> 2, ks8 = (c & 3) * 8;
            int gr = brow + row; gr = (gr < N) ? gr : (N - 1);
            size_t ga = (size_t)gr * 128 + k0 + ks8;
            int o = ((ks8 >> 3) * 64 + row) * 8;
            *(uint4*)&Ah[o] = *(const uint4*)(jb.Ah + ga);
            *(uint4*)&Al[o] = *(const uint4*)(jb.Al + ga);
        }
        #pragma unroll
        for (int it = 0; it < 2; it++) {
            int c = tid + it*256;
            int col = c >> 2, ks8 = (c & 3) * 8;
            size_t go = (size_t)col * 128 + k0 + ks8;
            int o = ((ks8 >> 3) * 128 + col) * 8;
            *(uint4*)&Bh[o] = *(const uint4*)(jb.Wh + go);
            *(uint4*)&Bl[o] = *(const uint4*)(jb.Wl + go);
        }
        __syncthreads();
        bf16x8 ah[2], al_[2], bh[4], bl_[4];
        #pragma unroll
        for (int i = 0; i < 2; i++) {
            int o = (lkg*64 + wr*32 + i*16 + lrow) * 8;
            ah[i] = *(const bf16x8*)&Ah[o];
            al_[i] = *(const bf16x8*)&Al[o];
        }
        #pragma unroll
        for (int j = 0; j < 4; j++) {
            int o = (lkg*128 + wc*64 + j*16 + lrow) * 8;
            bh[j] = *(const bf16x8*)&Bh[o];
            bl_[j] = *(const bf16x8*)&Bl[o];
        }
        #pragma unroll
        for (int i = 0; i < 2; i++)
            #pragma unroll
            for (int j = 0; j < 4; j++) {
                acc[i][j] = __builtin_amdgcn_mfma_f32_16x16x32_bf16(ah[i], bh[j], acc[i][j], 0,0,0);
                acc[i][j] = __builtin_amdgcn_mfma_f32_16x16x32_bf16(ah[i], bl_[j], acc[i][j], 0,0,0);
                acc[i][j] = __builtin_amdgcn_mfma_f32_16x16x32_bf16(al_[i], bh[j], acc[i][j], 0,0,0);
            }
        __syncthreads();
    }

    float beta = 0.f;
    if (jb.mode == 1) beta = 1.f / (1.f + __expf(-jb.skipv[0]));
    #pragma unroll
    for (int i = 0; i < 2; i++) {
        int rbase = brow + wr*32 + i*16 + (lane >> 4) * 4;
        #pragma unroll
        for (int j = 0; j < 4; j++) {
            int col = wc*64 + j*16 + lrow;
            float bv = jb.bias[col];
            #pragma unroll
            for (int rr = 0; rr < 4; rr++) {
                int gr = rbase + rr;
                if (gr < N) {
                    size_t idx = (size_t)gr * 128 + col;
                    float cv = acc[i][j][rr] + bv;
                    if (jb.mode == 2) {
                        ((unsigned short*)jb.C)[idx] = bf16_rn(cv);
                    } else {
                        if (jb.mode == 1) {
                            float r = jb.res[idx];
                            cv = beta * cv + (1.f - beta) * r;
                        }
                        ((float*)jb.C)[idx] = cv;
                        if (jb.Ch) {
                            unsigned short h, l; split2(cv, h, l);
                            jb.Ch[idx] = h; jb.Cl[idx] = l;
                        }
                    }
                }
            }
        }
    }
}

// ---- fused attention: 2-way split online-softmax state, defer-rescale ----
struct AttnP {
    const unsigned int* q[5];
    const unsigned int* ke[5];
    const unsigned int* ve[5];
    const int* off[5];
    const int* csr[5];
    float* out[5];
    const float* prel;
    int base[6];
    int ndst[5];
};

__global__ __launch_bounds__(256) void attn_fused(AttnP p) {
    int b = blockIdx.x;
    int z = 0;
    #pragma unroll
    for (int k = 1; k < 5; k++) if (b >= p.base[k]) z = k;
    int node = (b - p.base[z]) * 4 + (threadIdx.x >> 6);
    if (node >= p.ndst[z]) return;
    int lane = threadIdx.x & 63;
    int e0 = p.off[z][node], e1 = p.off[z][node + 1];
    float2* o = (float2*)(p.out[z] + (size_t)node * 128 + lane * 2);
    if (e0 == e1) { *o = make_float2(0.f, 0.f); return; }
    unsigned int qu = p.q[z][(size_t)node * 64 + lane];
    float qx = blo(qu), qy = bhi(qu);
    float pr = p.prel[z * 8 + (lane >> 3)] * 0.25f;
    const unsigned int* KE = p.ke[z];
    const unsigned int* VE = p.ve[z];
    const int* srcs = p.csr[z];
    float m0 = -INFINITY, s0 = 0.f, ax0 = 0.f, ay0 = 0.f;
    float m1 = -INFINITY, s1 = 0.f, ax1 = 0.f, ay1 = 0.f;
    int i = e0;
    for (; i + 2 <= e1; i += 2) {
        int sa = srcs[i], sb = srcs[i+1];
        unsigned int ka = KE[(size_t)sa*64 + lane];
        unsigned int kb = KE[(size_t)sb*64 + lane];
        unsigned int va = VE[(size_t)sa*64 + lane];
        unsigned int vb = VE[(size_t)sb*64 + lane];
        float pa = qx*blo(ka) + qy*bhi(ka);
        float pb = qx*blo(kb) + qy*bhi(kb);
        pa += __shfl_xor(pa, 1); pb += __shfl_xor(pb, 1);
        pa += __shfl_xor(pa, 2); pb += __shfl_xor(pb, 2);
        pa += __shfl_xor(pa, 4); pb += __shfl_xor(pb, 4);
        float aa = pa * pr, ab = pb * pr;
        if (aa > m0) { float cc = __expf(m0 - aa); s0 *= cc; ax0 *= cc; ay0 *= cc; m0 = aa; }
        float pea = __expf(aa - m0);
        s0 += pea; ax0 += pea * blo(va); ay0 += pea * bhi(va);
        if (ab > m1) { float cc = __expf(m1 - ab); s1 *= cc; ax1 *= cc; ay1 *= cc; m1 = ab; }
        float peb = __expf(ab - m1);
        s1 += peb; ax1 += peb * blo(vb); ay1 += peb * bhi(vb);
    }
    if (i < e1) {
        int sa = srcs[i];
        unsigned int ka = KE[(size_t)sa*64 + lane];
        unsigned int va = VE[(size_t)sa*64 + lane];
        float pa = qx*blo(ka) + qy*bhi(ka);
        pa += __shfl_xor(pa, 1);
        pa += __shfl_xor(pa, 2);
        pa += __shfl_xor(pa, 4);
        float aa = pa * pr;
        if (aa > m0) { float cc = __expf(m0 - aa); s0 *= cc; ax0 *= cc; ay0 *= cc; m0 = aa; }
        float pea = __expf(aa - m0);
        s0 += pea; ax0 += pea * blo(va); ay0 += pea * bhi(va);
    }
    if (s1 > 0.f) {
        float M = fmaxf(m0, m1);
        float c0 = __expf(m0 - M), c1 = __expf(m1 - M);
        s0 = s0*c0 + s1*c1;
        ax0 = ax0*c0 + ax1*c1;
        ay0 = ay0*c0 + ay1*c1;
    }
    float inv = 1.f / (s0 + 1e-16f);
    *o = make_float2(ax0 * inv, ay0 * inv);
}

// ---- protein init: xsA = pA + pB, plus split ----
__global__ __launch_bounds__(256) void presplit_prot(const float* __restrict__ pA, const float* __restrict__ pB,
        float* __restrict__ xs, unsigned short* __restrict__ xh, unsigned short* __restrict__ xl, int n4) {
    int i = blockIdx.x * 256 + threadIdx.x;
    if (i >= n4) return;
    float4 a = ((const float4*)pA)[i];
    float4 b = ((const float4*)pB)[i];
    float4 v = make_float4(a.x+b.x, a.y+b.y, a.z+b.z, a.w+b.w);
    ((float4*)xs)[i] = v;
    ushort4 h, l;
    split2(v.x, h.x, l.x); split2(v.y, h.y, l.y);
    split2(v.z, h.z, l.z); split2(v.w, h.w, l.w);
    ((ushort4*)xh)[i] = h; ((ushort4*)xl)[i] = l;
}

// ---- CSR build ----
struct CsrP {
    const int* esrc[5]; const int* edst[5];
    int* cnt[5]; int* off[5]; int* off2[5]; int* csr[5]; int* bsum[5];
    int E[5]; int N[5]; int nb[5];
};

__global__ __launch_bounds__(256) void csr_hist(CsrP p) {
    int z = blockIdx.z;
    int i = blockIdx.x * 256 + threadIdx.x;
    if (i < p.E[z]) atomicAdd(&p.cnt[z][p.edst[z][i]], 1);
}

__global__ __launch_bounds__(256) void csr_p1(CsrP p) {
    int z = blockIdx.z, b = blockIdx.x;
    int N = p.N[z];
    if (b * 1024 >= N) return;
    const int* cnt = p.cnt[z];
    __shared__ int wtot[4];
    int tid = threadIdx.x, lane = tid & 63, w = tid >> 6;
    int base = b * 1024 + tid * 4;
    int s = 0;
    #pragma unroll
    for (int k = 0; k < 4; k++) { int i = base + k; if (i < N) s += cnt[i]; }
    int incl = s;
    #pragma unroll
    for (int o = 1; o < 64; o <<= 1) { int t = __shfl_up(incl, o); if (lane >= o) incl += t; }
    if (lane == 63) wtot[w] = incl;
    __syncthreads();
    if (tid == 0) p.bsum[z][b] = wtot[0] + wtot[1] + wtot[2] + wtot[3];
}

__global__ void csr_p2(CsrP p) {
    int z = blockIdx.z;
    if (threadIdx.x == 0) {
        int nb = p.nb[z]; int run = 0; int* bs = p.bsum[z];
        for (int b = 0; b < nb; b++) { int t = bs[b]; bs[b] = run; run += t; }
        p.off[z][p.N[z]] = run;
        p.off2[z][p.N[z]] = run;
    }
}

__global__ __launch_bounds__(256) void csr_p3(CsrP p) {
    int z = blockIdx.z, b = blockIdx.x;
    int N = p.N[z];
    if (b * 1024 >= N) return;
    const int* cnt = p.cnt[z]; int* off = p.off[z]; int* off2 = p.off2[z];
    __shared__ int wtot[4];
    int tid = threadIdx.x, lane = tid & 63, w = tid >> 6;
    int base = b * 1024 + tid * 4;
    int v0=0,v1=0,v2=0,v3=0;
    if (base+0 < N) v0 = cnt[base+0];
    if (base+1 < N) v1 = cnt[base+1];
    if (base+2 < N) v2 = cnt[base+2];
    if (base+3 < N) v3 = cnt[base+3];
    int tsum = v0+v1+v2+v3;
    int incl = tsum;
    #pragma unroll
    for (int o = 1; o < 64; o <<= 1) { int t = __shfl_up(incl, o); if (lane >= o) incl += t; }
    if (lane == 63) wtot[w] = incl;
    __syncthreads();
    int we = 0;
    for (int k = 0; k < w; k++) we += wtot[k];
    int texcl = we + incl - tsum + p.bsum[z][b];
    int o0 = texcl, o1 = texcl+v0, o2 = texcl+v0+v1, o3 = texcl+v0+v1+v2;
    if (base+0 < N) { off[base+0]=o0; off2[base+0]=o0; }
    if (base+1 < N) { off[base+1]=o1; off2[base+1]=o1; }
    if (base+2 < N) { off[base+2]=o2; off2[base+2]=o2; }
    if (base+3 < N) { off[base+3]=o3; off2[base+3]=o3; }
}

__global__ __launch_bounds__(256) void csr_scatter(CsrP p) {
    int z = blockIdx.z;
    int i = blockIdx.x * 256 + threadIdx.x;
    if (i < p.E[z]) {
        int d = p.edst[z][i];
        int pos = atomicAdd(&p.off2[z][d], 1);
        p.csr[z][pos] = p.esrc[z][i];
    }
}

extern "C" void kernel_launch(void* const* d_in, const int* in_sizes, int n_in,
                              void* d_out, int out_size, void* d_ws, size_t ws_size,
                              hipStream_t stream)
{
    const float* xin[3] = {(const float*)d_in[0], (const float*)d_in[1], (const float*)d_in[2]};
    const int FIN[3] = {512, 1024, 128};
    const int KBITS[3] = {9, 10, 7};
    int ns[3];
    for (int t = 0; t < 3; t++) ns[t] = in_sizes[t] / FIN[t];
    const int* esrc[5]; const int* edst[5]; int E[5];
    for (int e = 0; e < 5; e++) { esrc[e] = (const int*)d_in[3+2*e]; edst[e] = (const int*)d_in[4+2*e]; E[e] = in_sizes[3+2*e]; }
    const float* Win[3] = {(const float*)d_in[13], (const float*)d_in[15], (const float*)d_in[17]};
    const float* bin[3] = {(const float*)d_in[14], (const float*)d_in[16], (const float*)d_in[18]};
    const float* Wk = (const float*)d_in[19]; const float* Wq = (const float*)d_in[20];
    const float* Wv = (const float*)d_in[21]; const float* Wa = (const float*)d_in[22];
    const float* bk = (const float*)d_in[23]; const float* bq = (const float*)d_in[24];
    const float* bv = (const float*)d_in[25]; const float* ba = (const float*)d_in[26];
    const float* skipp = (const float*)d_in[27];
    const float* a_rel = (const float*)d_in[28];
    const float* m_rel = (const float*)d_in[29];
    const float* p_rel = (const float*)d_in[30];

    static const int ST[5] = {2,0,0,1,1}, DT[5] = {0,2,1,0,1};

    int NTOT = ns[0] + ns[1] + ns[2];
    int toff[3] = {0, ns[0], ns[0] + ns[1]};
    int maxN = ns[0]; for (int t = 1; t < 3; t++) if (ns[t] > maxN) maxN = ns[t];
    int maxE = E[0]; for (int e = 1; e < 5; e++) if (E[e] > maxE) maxE = E[e];

    // ---- workspace carve ----
    float* fp = (float*)d_ws;
    float* xsA = fp; fp += (size_t)NTOT*HID;
    float* xsB = fp; fp += (size_t)NTOT*HID;
    float* oaccA = fp; fp += (size_t)NTOT*HID;
    float* oaccB = fp; fp += (size_t)NTOT*HID;
    float* pA = fp; fp += (size_t)ns[1]*HID;
    float* pB = fp; fp += (size_t)ns[1]*HID;
    float* bke = fp; fp += 10*128;
    float* bve = fp; fp += 10*128;
    unsigned short* up = (unsigned short*)fp;
    unsigned short* xh = up; up += (size_t)NTOT*HID;
    unsigned short* xl = up; up += (size_t)NTOT*HID;
    unsigned short* qbf = up; up += (size_t)NTOT*HID;
    unsigned short* kebf[5]; unsigned short* vebf[5];
    for (int e = 0; e < 5; e++) {
        kebf[e] = up; up += (size_t)ns[ST[e]]*HID;
        vebf[e] = up; up += (size_t)ns[ST[e]]*HID;
    }
    unsigned short* wih[3]; unsigned short* wil[3];
    for (int t = 0; t < 3; t++) { wih[t] = up; up += (size_t)FIN[t]*HID; wil[t] = up; up += (size_t)FIN[t]*HID; }
    unsigned short* wqh = up; up += 6*16384; unsigned short* wql = up; up += 6*16384;
    unsigned short* wah = up; up += 6*16384; unsigned short* wal = up; up += 6*16384;
    unsigned short* wkeh = up; up += 10*16384; unsigned short* wkel = up; up += 10*16384;
    unsigned short* wveh = up; up += 10*16384; unsigned short* wvel = up; up += 10*16384;
    uintptr_t ip_ = ((uintptr_t)up + 255) & ~(uintptr_t)255;
    int* ip = (int*)ip_;
    int* off[5]; int* off2[5]; int* csrc[5]; int* cntp[5]; int* bsump[5];
    for (int e = 0; e < 5; e++) { off[e] = ip; ip += ns[DT[e]] + 1; }
    for (int e = 0; e < 5; e++) { off2[e] = ip; ip += ns[DT[e]] + 1; }
    for (int e = 0; e < 5; e++) { csrc[e] = ip; ip += E[e]; }
    int* cntbase = ip; int cnt_tot = 0;
    for (int e = 0; e < 5; e++) { cntp[e] = cntbase + cnt_tot; cnt_tot += ns[DT[e]]; }
    ip += cnt_tot;
    for (int e = 0; e < 5; e++) { bsump[e] = ip; ip += 64; }

    // ---- weight prep ----
    WJobs wj;
    for (int t = 0; t < 3; t++) { wj.in[t]=Win[t]; wj.hi[t]=wih[t]; wj.lo[t]=wil[t]; wj.kbits[t]=KBITS[t]; }
    for (int j = 0; j < 6; j++) {
        wj.in[3+j]=Wq + (size_t)j*16384; wj.hi[3+j]=wqh + (size_t)j*16384; wj.lo[3+j]=wql + (size_t)j*16384; wj.kbits[3+j]=7;
        wj.in[9+j]=Wa + (size_t)j*16384; wj.hi[9+j]=wah + (size_t)j*16384; wj.lo[9+j]=wal + (size_t)j*16384; wj.kbits[9+j]=7;
    }
    wprep<<<dim3(512, 15), 256, 0, stream>>>(wj);
    fuse_w<<<dim3(64, 20), 256, 0, stream>>>(Wk, Wv, a_rel, m_rel, wkeh, wkel, wveh, wvel);
    fuse_b<<<dim3(1, 20), 128, 0, stream>>>(bk, bv, a_rel, m_rel, bke, bve);

    // ---- CSR build ----
    CsrP cp;
    for (int e = 0; e < 5; e++) {
        cp.esrc[e]=esrc[e]; cp.edst[e]=edst[e];
        cp.cnt[e]=cntp[e]; cp.off[e]=off[e]; cp.off2[e]=off2[e]; cp.csr[e]=csrc[e]; cp.bsum[e]=bsump[e];
        cp.E[e]=E[e]; cp.N[e]=ns[DT[e]]; cp.nb[e]=(ns[DT[e]] + 1023)/1024;
    }
    int nbmax = (maxN + 1023) / 1024;
    hipMemsetAsync(cntbase, 0, (size_t)cnt_tot * 4, stream);
    csr_hist<<<dim3((maxE+255)/256, 1, 5), 256, 0, stream>>>(cp);
    csr_p1<<<dim3(nbmax, 1, 5), 256, 0, stream>>>(cp);
    csr_p2<<<dim3(1, 1, 5), 64, 0, stream>>>(cp);
    csr_p3<<<dim3(nbmax, 1, 5), 256, 0, stream>>>(cp);
    csr_scatter<<<dim3((maxE+255)/256, 1, 5), 256, 0, stream>>>(cp);

    // ---- initial projections (split fused into epilogue; protein split-K summed after) ----
    IJobs ij;
    ij.j[0] = { xin[0], wih[0], wil[0], bin[0], xsA, xh, xl,                ns[0], 512, 0, 512 };
    ij.j[1] = { xin[2], wih[2], wil[2], bin[2], xsA + (size_t)toff[2]*HID,
                xh + (size_t)toff[2]*HID, xl + (size_t)toff[2]*HID,         ns[2], 128, 0, 128 };
    ij.j[2] = { xin[1], wih[1], wil[1], bin[1], pA, nullptr, nullptr,       ns[1], 1024, 0, 512 };
    ij.j[3] = { xin[1], wih[1], wil[1], nullptr, pB, nullptr, nullptr,      ns[1], 1024, 512, 1024 };
    int gx = (maxN + 63) / 64;
    gemm_init<<<dim3(gx, 4), 256, 0, stream>>>(ij);

    int pn4 = ns[1] * HID / 4;
    presplit_prot<<<(pn4+255)/256, 256, 0, stream>>>(pA, pB,
        xsA + (size_t)toff[1]*HID, xh + (size_t)toff[1]*HID, xl + (size_t)toff[1]*HID, pn4);

    float* outp = (float*)d_out;

    int abase[6]; abase[0] = 0;
    for (int e = 0; e < 5; e++) abase[e+1] = abase[e] + (ns[DT[e]] + 3) / 4;
    float* outsel[5] = { oaccA, oaccA + (size_t)toff[2]*HID, oaccA + (size_t)toff[1]*HID,
                         oaccB, oaccB + (size_t)toff[1]*HID };

    for (int l = 0; l < 2; l++) {
        float* cur = (l == 0) ? xsA : xsB;

        // main GEMM: q + ke/ve for all relations (one dispatch, 13 jobs, bf16 out)
        Jobs js = {};
        int ji = 0;
        for (int t = 0; t < 3; t++) {
            int m = l*3 + t;
            js.j[ji++] = { xh + (size_t)toff[t]*HID, xl + (size_t)toff[t]*HID, nullptr, nullptr,
                           wqh + (size_t)m*16384, wql + (size_t)m*16384,
                           bq + (size_t)m*HID, nullptr, nullptr,
                           qbf + (size_t)toff[t]*HID, nullptr, nullptr, ns[t], 2 };
            for (int e = 0; e < 5; e++) {
                if (ST[e] != t) continue;
                int mm = l*5 + e;
                js.j[ji++] = { xh + (size_t)toff[t]*HID, xl + (size_t)toff[t]*HID, nullptr, nullptr,
                               wkeh + (size_t)mm*16384, wkel + (size_t)mm*16384,
                               bke + mm*128, nullptr, nullptr,
                               kebf[e], nullptr, nullptr, ns[t], 2 };
                js.j[ji++] = { xh + (size_t)toff[t]*HID, xl + (size_t)toff[t]*HID, nullptr, nullptr,
                               wveh + (size_t)mm*16384, wvel + (size_t)mm*16384,
                               bve + mm*128, nullptr, nullptr,
                               vebf[e], nullptr, nullptr, ns[t], 2 };
            }
        }
        gemm_ws<<<dim3(gx, 13), 256, 0, stream>>>(js);

        // fused attention (one dispatch; deg-0 nodes write zeros)
        AttnP ap;
        for (int e = 0; e < 5; e++) {
            ap.q[e] = (const unsigned int*)(qbf + (size_t)toff[DT[e]]*HID);
            ap.ke[e] = (const unsigned int*)kebf[e];
            ap.ve[e] = (const unsigned int*)vebf[e];
            ap.off[e] = off[e]; ap.csr[e] = csrc[e];
            ap.out[e] = outsel[e];
            ap.ndst[e] = ns[DT[e]];
        }
        for (int k = 0; k < 6; k++) ap.base[k] = abase[k];
        ap.prel = p_rel + l*40;
        attn_fused<<<abase[5], 256, 0, stream>>>(ap);

        // epilogue: gelu(oaccA[+oaccB]) staged inline; split-out for next layer when l==0
        Jobs je = {};
        for (int t = 0; t < 3; t++) {
            int m = l*3 + t;
            const float* A1 = oaccA + (size_t)toff[t]*HID;
            const float* A2 = (t == 2) ? nullptr : (oaccB + (size_t)toff[t]*HID);
            je.j[t] = { nullptr, nullptr, A1, A2,
                        wah + (size_t)m*16384, wal + (size_t)m*16384,
                        ba + (size_t)m*HID,
                        cur + (size_t)toff[t]*HID, skipp + m,
                        ((l == 0) ? xsB : outp) + (size_t)toff[t]*HID,
                        (l == 0) ? xh + (size_t)toff[t]*HID : nullptr,
                        (l == 0) ? xl + (size_t)toff[t]*HID : nullptr,
                        ns[t], 1 };
        }
        gemm_ws<<<dim3(gx, 3), 256, 0, stream>>>(je);
    }
}